// Round 1
// baseline (685.562 us; speedup 1.0000x reference)
//
#include <hip/hip_runtime.h>
#include <math.h>

// Problem dims (fixed)
#define BB   16
#define SS   2048
#define DIN  256
#define DEMB 512
#define DKQ  512
#define DVV  512

typedef _Float16 f16;
typedef _Float16 half8  __attribute__((ext_vector_type(8)));
typedef _Float16 f16x4  __attribute__((ext_vector_type(4)));
typedef float    f32x4  __attribute__((ext_vector_type(4)));
typedef float    f32x16 __attribute__((ext_vector_type(16)));

#define GLOAD_LDS16(gp, lp)                                                        \
  __builtin_amdgcn_global_load_lds(                                                \
      (const __attribute__((address_space(1))) unsigned int*)(gp),                 \
      (__attribute__((address_space(3))) unsigned int*)(lp), 16, 0, 0)

// V slot permute: decorrelates LDS bank-start across dv rows (2-way max)
__device__ __forceinline__ int vperm(int dv) { return (dv ^ (dv >> 2)) & 3; }

// ---------------------------------------------------------------------------
// Kernel 0: split x (fp32) -> Xh, Xl (fp16 pair, exact to ~2^-22)
// ---------------------------------------------------------------------------
__global__ __launch_bounds__(256) void prep_x(
    const float* __restrict__ x, f16* __restrict__ Xh, f16* __restrict__ Xl)
{
    int idx = blockIdx.x * 256 + threadIdx.x;
    float4 v = ((const float4*)x)[idx];
    f16x4 h, l;
    h.x = (f16)v.x; l.x = (f16)(v.x - (float)h.x);
    h.y = (f16)v.y; l.y = (f16)(v.y - (float)h.y);
    h.z = (f16)v.z; l.z = (f16)(v.z - (float)h.z);
    h.w = (f16)v.w; l.w = (f16)(v.w - (float)h.w);
    ((f16x4*)Xh)[idx] = h;
    ((f16x4*)Xl)[idx] = l;
}

// ---------------------------------------------------------------------------
// Kernel 1: fuse weights W' = W_embed @ W (fp32 math), output TRANSPOSED
// fp16 split:  Wth/Wtl [z][n=512][k=256]
// ---------------------------------------------------------------------------
__global__ __launch_bounds__(256) void fuse_weights(
    const float* __restrict__ We, const float* __restrict__ Wk,
    const float* __restrict__ Wq, const float* __restrict__ Wv,
    f16* __restrict__ Wth, f16* __restrict__ Wtl)
{
    int idx = blockIdx.x * 256 + threadIdx.x;
    int n = idx & 511;
    int m = (idx >> 9) & 255;
    int z = idx >> 17;
    const float* Wsrc = (z == 0) ? Wk : (z == 1) ? Wq : Wv;
    float sum = 0.f;
#pragma unroll 8
    for (int kk = 0; kk < DEMB; ++kk)
        sum += We[m * DEMB + kk] * Wsrc[kk * 512 + n];
    f16 h = (f16)sum;
    f16 l = (f16)(sum - (float)h);
    Wth[(size_t)z * 131072 + n * 256 + m] = h;
    Wtl[(size_t)z * 131072 + n * 256 + m] = l;
}

// ---------------------------------------------------------------------------
// Kernel 2: MFMA projections, 3-term fp16 split (Ah*Bh + Al*Bh + Ah*Bl).
// Tile 128x128, K-chunk 64, 4 waves. global_load_lds staging.
//   z=0 -> Kh [row][512]; z=1 -> Qh [row][512];
//   z=2 -> Vt2 [b][tile(64)][dv(512)][32 keys], 16B slots permuted by vperm(dv)
// ---------------------------------------------------------------------------
#define QAH 0
#define QAL 8192
#define QBH 16384
#define QBL 24576

__global__ __launch_bounds__(256) void qkv_gemm(
    const f16* __restrict__ Xh, const f16* __restrict__ Xl,
    const f16* __restrict__ Wth, const f16* __restrict__ Wtl,
    f16* __restrict__ Kh, f16* __restrict__ Qh, f16* __restrict__ Vt2)
{
    __shared__ __align__(16) short smq[32768];   // 64 KB

    const int tid  = threadIdx.x;
    const int lane = tid & 63;
    const int w    = tid >> 6;
    const int z    = blockIdx.z;
    const int m0   = blockIdx.y * 128;
    const int n0   = blockIdx.x * 128;
    const int l15  = lane & 15;
    const int quad = lane >> 4;
    const int wm   = (w >> 1) * 64, wn = (w & 1) * 64;

    const f16* Bh = Wth + (size_t)z * 131072;
    const f16* Bl = Wtl + (size_t)z * 131072;

    f32x4 acc[4][4];
#pragma unroll
    for (int i = 0; i < 4; ++i)
#pragma unroll
        for (int j = 0; j < 4; ++j) acc[i][j] = (f32x4){0.f, 0.f, 0.f, 0.f};

    const int lrow = lane >> 3;
    const int lswz = ((lane & 7) ^ (lrow & 7)) << 3;

    for (int c = 0; c < 4; ++c) {
        const int k0 = c * 64;
#pragma unroll
        for (int i = 0; i < 4; ++i) {
            int r0 = w * 32 + i * 8;
            int row = r0 + lrow;
            GLOAD_LDS16(Xh + (size_t)(m0 + row) * 256 + k0 + lswz, smq + QAH + r0 * 64);
            GLOAD_LDS16(Xl + (size_t)(m0 + row) * 256 + k0 + lswz, smq + QAL + r0 * 64);
            GLOAD_LDS16(Bh + (size_t)(n0 + row) * 256 + k0 + lswz, smq + QBH + r0 * 64);
            GLOAD_LDS16(Bl + (size_t)(n0 + row) * 256 + k0 + lswz, smq + QBL + r0 * 64);
        }
        __syncthreads();
#pragma unroll
        for (int ks = 0; ks < 2; ++ks) {
            const int kg = ks * 4 + quad;
            const int rsw = (kg ^ (l15 & 7)) << 3;
            half8 ah[4], al[4], bh[4], bl[4];
#pragma unroll
            for (int i = 0; i < 4; ++i) {
                int m = wm + i * 16 + l15;
                int n = wn + i * 16 + l15;
                ah[i] = *(const half8*)(smq + QAH + m * 64 + rsw);
                al[i] = *(const half8*)(smq + QAL + m * 64 + rsw);
                bh[i] = *(const half8*)(smq + QBH + n * 64 + rsw);
                bl[i] = *(const half8*)(smq + QBL + n * 64 + rsw);
            }
#pragma unroll
            for (int mi = 0; mi < 4; ++mi)
#pragma unroll
                for (int ni = 0; ni < 4; ++ni) {
                    acc[mi][ni] = __builtin_amdgcn_mfma_f32_16x16x32_f16(ah[mi], bh[ni], acc[mi][ni], 0, 0, 0);
                    acc[mi][ni] = __builtin_amdgcn_mfma_f32_16x16x32_f16(al[mi], bh[ni], acc[mi][ni], 0, 0, 0);
                    acc[mi][ni] = __builtin_amdgcn_mfma_f32_16x16x32_f16(ah[mi], bl[ni], acc[mi][ni], 0, 0, 0);
                }
        }
        __syncthreads();
    }

    // ---- epilogue via LDS (stride 136 shorts) ----
    if (z < 2) {
#pragma unroll
        for (int mi = 0; mi < 4; ++mi)
#pragma unroll
            for (int ni = 0; ni < 4; ++ni)
#pragma unroll
                for (int r = 0; r < 4; ++r)
                    *(f16*)(smq + (wm + mi * 16 + quad * 4 + r) * 136 + wn + ni * 16 + l15) =
                        (f16)acc[mi][ni][r];
        __syncthreads();
        f16* Out = (z == 0) ? Kh : Qh;
        int cg = tid & 15;
#pragma unroll
        for (int j = 0; j < 8; ++j) {
            int row = j * 16 + (tid >> 4);
            half8 v = *(const half8*)(smq + row * 136 + cg * 8);
            *(half8*)&Out[(size_t)(m0 + row) * 512 + n0 + cg * 8] = v;
        }
    } else {
        // transpose in LDS: [dv_local][key_local]
#pragma unroll
        for (int mi = 0; mi < 4; ++mi)
#pragma unroll
            for (int ni = 0; ni < 4; ++ni)
#pragma unroll
                for (int r = 0; r < 4; ++r)
                    *(f16*)(smq + (wn + ni * 16 + l15) * 136 + wm + mi * 16 + quad * 4 + r) =
                        (f16)acc[mi][ni][r];
        __syncthreads();
        int bb = m0 >> 11, kb0 = m0 & 2047;
        int cg = tid & 15;
#pragma unroll
        for (int j = 0; j < 8; ++j) {
            int dvr = j * 16 + (tid >> 4);
            int dv  = n0 + dvr;
            half8 v = *(const half8*)(smq + dvr * 136 + cg * 8);
            int t  = (kb0 >> 5) + (cg >> 2);     // key tile
            int s  = (cg & 3) ^ vperm(dv);       // permuted 16B slot
            *(half8*)&Vt2[(((size_t)bb * 64 + t) * 512 + dv) * 32 + s * 8] = v;
        }
    }
}

// ---------------------------------------------------------------------------
// Kernel 3: MFMA flash attention.
// ONE 8-wave block per CU (grid 256, 128 q-rows/block), K AND V double-
// buffered in LDS (150.6 KB), raw s_barrier with hand-placed waitcnt:
//   top barrier : s_waitcnt vmcnt(0)  -- stage(t) landed; full-tile window
//   mid barrier : s_waitcnt lgkmcnt(0) only -- stage(t+1) stays in flight
// Per-wave tiling unchanged (16q x 32keys scores; 32q x 256dv PV) so regs
// stay at 2 waves/SIMD. Defer-max (THR=8) makes O-rescale rare. XCD swizzle:
// all 16 q-blocks of a batch on one XCD so K/V stream stays L2-resident.
// ---------------------------------------------------------------------------
#define LK0 0        // K tile buf0: 32 keys x 512 d     = 16384 shorts
#define LK1 16384    // K tile buf1
#define LV0 32768    // V tile buf0: 512 dv x 32 keys    = 16384 shorts
#define LV1 49152    // V tile buf1
#define LP  65536    // P: 128 q x stride 72              =  9216 shorts
#define LA  74752    // alpha[128] floats                 =   256 shorts
#define LL  75008    // l[128] floats                     =   256 shorts
#define LF  75264    // flags[8] ints                     =    16 shorts
#define LTOT 75280   // 150560 bytes (<160 KiB)

#define RESCALE_THR 8.0f

__global__ __launch_bounds__(512, 2) void attn2(
    const f16* __restrict__ Qh, const f16* __restrict__ Kh,
    const f16* __restrict__ Vt2, float* __restrict__ Y)
{
    __shared__ __align__(16) short sm[LTOT];

    const int tid  = threadIdx.x;
    const int lane = tid & 63;
    const int w    = tid >> 6;                    // 0..7
    // XCD-aware decode: xcd = gid&7; b = (gid&7) + 8*(gid>>7); q0 = ((gid>>3)&15)*128
    const int gid  = blockIdx.x;
    const int b    = (gid & 7) + ((gid >> 7) << 3);
    const int q0   = ((gid >> 3) & 15) << 7;
    const int l15  = lane & 15;
    const int quad = lane >> 4;
    const int l31  = lane & 31;
    const int lhi  = lane >> 5;
    const int qquad = w >> 1, dvhalf = w & 1;     // PV mapping: 4 q-quads x 2 dv-halves

    const f16* Khb  = Kh  + (size_t)b * SS * 512;
    const f16* Vt2b = Vt2 + (size_t)b * 64 * 512 * 32;

    // ---- Q fragments (resident): wave w, q rows q0+16w .. +15 ----
    half8 qh[16];
    {
        const half8* qhp = (const half8*)(Qh + ((size_t)(b * SS + q0 + w * 16 + l15)) * 512);
#pragma unroll
        for (int ks = 0; ks < 16; ++ks) qh[ks] = qhp[ks * 4 + quad];
    }

    f32x16 O[8];
#pragma unroll
    for (int n = 0; n < 8; ++n)
#pragma unroll
        for (int r = 0; r < 16; ++r) O[n][r] = 0.f;

    float m_pr[4] = {-1e30f, -1e30f, -1e30f, -1e30f};
    float l_r[4]  = {0.f, 0.f, 0.f, 0.f};

    // 8 waves x 4 instrs = 32 KB per tile for each of K and V
    auto stage_K = [&](int t, int lk) {
        const int kb = t * 32;
#pragma unroll
        for (int i = 0; i < 4; ++i) {
            int key = w * 4 + i;
            const f16* g = Khb + ((size_t)(kb + key)) * 512 + ((lane ^ (key & 15)) << 3);
            GLOAD_LDS16(g, sm + lk + key * 512);
        }
    };
    auto stage_V = [&](int t, int lv) {
        const f16* gbase = Vt2b + (size_t)t * 16384 + lane * 8;
#pragma unroll
        for (int i = 0; i < 4; ++i) {
            int off = (w * 4 + i) * 512;
            GLOAD_LDS16(gbase + off, sm + lv + off);
        }
    };

    float* aptr = (float*)(sm + LA);
    float* lptr = (float*)(sm + LL);
    int*   fptr = (int*)(sm + LF);

    stage_K(0, LK0); stage_V(0, LV0);

    auto tile = [&](int t, int LKc, int LVc, int LKn, int LVn, bool doStage) {
        // ---- top barrier: K(t)/V(t) landed (issued a full tile ago) ----
        asm volatile("s_waitcnt vmcnt(0)" ::: "memory");
        __builtin_amdgcn_s_barrier();
        __builtin_amdgcn_sched_barrier(0);

        // prefetch tile t+1 into the other buffers; drains at NEXT top barrier
        if (doStage) { stage_K(t + 1, LKn); stage_V(t + 1, LVn); }

        // ---- scores: S = Qh * Kh^T (16x16x32), 16 q x 32 keys per wave ----
        f32x4 S[2];
        S[0] = (f32x4){0.f, 0.f, 0.f, 0.f};
        S[1] = (f32x4){0.f, 0.f, 0.f, 0.f};
        __builtin_amdgcn_s_setprio(1);
#pragma unroll
        for (int ks = 0; ks < 16; ++ks) {
#pragma unroll
            for (int n = 0; n < 2; ++n) {
                int key = n * 16 + l15;
                int ud  = ks * 4 + quad;
                half8 bf = *(const half8*)(sm + LKc + key * 512 + ((ud ^ l15) << 3));
                S[n] = __builtin_amdgcn_mfma_f32_16x16x32_f16(qh[ks], bf, S[n], 0, 0, 0);
            }
        }
        __builtin_amdgcn_s_setprio(0);

        // ---- online softmax with defer-max (T13, THR=8) ----
        float mx[4], sum[4], al[4];
#pragma unroll
        for (int r = 0; r < 4; ++r) mx[r] = fmaxf(S[0][r], S[1][r]);
#pragma unroll
        for (int off = 1; off < 16; off <<= 1)
#pragma unroll
            for (int r = 0; r < 4; ++r)
                mx[r] = fmaxf(mx[r], __shfl_xor(mx[r], off, 64));
#pragma unroll
        for (int r = 0; r < 4; ++r) {
            bool up  = mx[r] > m_pr[r] + RESCALE_THR;   // defer small max growth
            float mn = up ? mx[r] : m_pr[r];
            al[r]    = up ? __expf(m_pr[r] - mn) : 1.0f;
            m_pr[r]  = mn;
            sum[r]   = 0.f;
        }
#pragma unroll
        for (int n = 0; n < 2; ++n) {
#pragma unroll
            for (int r = 0; r < 4; ++r) {
                float p = __expf(S[n][r] - m_pr[r]);    // bounded by e^THR
                sum[r] += p;
                int q   = w * 16 + quad * 4 + r;
                int key = n * 16 + l15;
                *(f16*)(sm + LP + q * 72 + key) = (f16)p;
            }
        }
#pragma unroll
        for (int off = 1; off < 16; off <<= 1)
#pragma unroll
            for (int r = 0; r < 4; ++r)
                sum[r] += __shfl_xor(sum[r], off, 64);
#pragma unroll
        for (int r = 0; r < 4; ++r)
            l_r[r] = l_r[r] * al[r] + sum[r];
        bool any = (al[0] < 1.f) | (al[1] < 1.f) | (al[2] < 1.f) | (al[3] < 1.f);
        unsigned long long bm = __ballot(any);
        if (lane == 0) fptr[w] = (bm != 0ULL) ? 1 : 0;
        if (l15 == 0) {
#pragma unroll
            for (int r = 0; r < 4; ++r) aptr[w * 16 + quad * 4 + r] = al[r];
        }

        // ---- mid barrier: P/alpha/flags visible; NO vmem drain (prefetch
        //      of t+1 stays in flight across this barrier) ----
        asm volatile("s_waitcnt lgkmcnt(0)" ::: "memory");
        __builtin_amdgcn_s_barrier();
        __builtin_amdgcn_sched_barrier(0);

        // ---- O rescale (rare after defer-max warmup) ----
        if (fptr[2 * qquad] | fptr[2 * qquad + 1]) {
            float av[16];
#pragma unroll
            for (int r = 0; r < 16; ++r) {
                int row = (r & 3) + ((r >> 2) << 3) + (lhi << 2);
                av[r] = aptr[qquad * 32 + row];
            }
#pragma unroll
            for (int n = 0; n < 8; ++n)
#pragma unroll
                for (int r = 0; r < 16; ++r) O[n][r] *= av[r];
        }

        // ---- PV: O += P * V (32x32x16), 32 q x 256 dv per wave ----
        half8 pA[2];
#pragma unroll
        for (int ks = 0; ks < 2; ++ks) {
            int q  = qquad * 32 + l31;
            int uk = ks * 2 + lhi;
            pA[ks] = *(const half8*)(sm + LP + q * 72 + uk * 8);
        }
        __builtin_amdgcn_s_setprio(1);
#pragma unroll
        for (int ks = 0; ks < 2; ++ks) {
#pragma unroll
            for (int n = 0; n < 8; ++n) {
                int dv = dvhalf * 256 + n * 32 + l31;
                int uk = ks * 2 + lhi;
                half8 bf = *(const half8*)(sm + LVc + dv * 32 + ((uk ^ vperm(dv)) << 3));
                O[n] = __builtin_amdgcn_mfma_f32_32x32x16_f16(pA[ks], bf, O[n], 0, 0, 0);
            }
        }
        __builtin_amdgcn_s_setprio(0);
    };

    for (int t = 0; t < 64; t += 2) {
        tile(t,     LK0, LV0, LK1, LV1, true);
        tile(t + 1, LK1, LV1, LK0, LV0, t + 2 < 64);
    }

    // ---- epilogue: O /= l, store ----
    if (l15 == 0) {
#pragma unroll
        for (int r = 0; r < 4; ++r) lptr[w * 16 + quad * 4 + r] = l_r[r];
    }
    __syncthreads();
    float linv[16];
#pragma unroll
    for (int r = 0; r < 16; ++r) {
        int row = (r & 3) + ((r >> 2) << 3) + (lhi << 2);
        linv[r] = 1.0f / lptr[qquad * 32 + row];
    }
#pragma unroll
    for (int n = 0; n < 8; ++n) {
#pragma unroll
        for (int r = 0; r < 16; ++r) {
            int row = (r & 3) + ((r >> 2) << 3) + (lhi << 2);
            Y[((size_t)(b * SS + q0 + qquad * 32 + row)) * 512 + dvhalf * 256 + n * 32 + l31] =
                O[n][r] * linv[r];
        }
    }
}

// ---------------------------------------------------------------------------
// Host launcher
// ---------------------------------------------------------------------------
extern "C" void kernel_launch(void* const* d_in, const int* in_sizes, int n_in,
                              void* d_out, int out_size, void* d_ws, size_t ws_size,
                              hipStream_t stream)
{
    const float* x  = (const float*)d_in[0];
    const float* We = (const float*)d_in[1];
    const float* Wk = (const float*)d_in[2];
    const float* Wq = (const float*)d_in[3];
    const float* Wv = (const float*)d_in[4];
    float* out = (float*)d_out;

    const size_t WSZ = 3 * 256 * 512;          // 393216
    const size_t XSZ = (size_t)BB * SS * DIN;  // 8388608
    const size_t MSZ = (size_t)BB * SS * 512;  // 16777216

    f16* Wth = (f16*)d_ws;
    f16* Wtl = Wth + WSZ;
    f16* Xh  = Wtl + WSZ;
    f16* Xl  = Xh + XSZ;
    f16* Qh  = Xl + XSZ;
    f16* Kh  = Qh + MSZ;
    f16* Vt2 = Kh + MSZ;

    prep_x<<<dim3(XSZ / 4 / 256), dim3(256), 0, stream>>>(x, Xh, Xl);

    fuse_weights<<<dim3(1536), dim3(256), 0, stream>>>(We, Wk, Wq, Wv, Wth, Wtl);

    qkv_gemm<<<dim3(4, 256, 3), dim3(256), 0, stream>>>(
        Xh, Xl, Wth, Wtl, Kh, Qh, Vt2);

    attn2<<<dim3(256), dim3(512), 0, stream>>>(Qh, Kh, Vt2, out);
}

// Round 2
// 620.129 us; speedup vs baseline: 1.1055x; 1.1055x over previous
//
#include <hip/hip_runtime.h>
#include <math.h>

// Problem dims (fixed)
#define BB   16
#define SS   2048
#define DIN  256
#define DEMB 512
#define DKQ  512
#define DVV  512

typedef _Float16 f16;
typedef _Float16 half8  __attribute__((ext_vector_type(8)));
typedef _Float16 f16x4  __attribute__((ext_vector_type(4)));
typedef float    f32x4  __attribute__((ext_vector_type(4)));
typedef float    f32x16 __attribute__((ext_vector_type(16)));

#define GLOAD_LDS16(gp, lp)                                                        \
  __builtin_amdgcn_global_load_lds(                                                \
      (const __attribute__((address_space(1))) unsigned int*)(gp),                 \
      (__attribute__((address_space(3))) unsigned int*)(lp), 16, 0, 0)

// V slot permute: decorrelates LDS bank-start across dv rows (2-way max)
__device__ __forceinline__ int vperm(int dv) { return (dv ^ (dv >> 2)) & 3; }

// ---------------------------------------------------------------------------
// Kernel 0: split x (fp32) -> Xh, Xl (fp16 pair, exact to ~2^-22)
// ---------------------------------------------------------------------------
__global__ __launch_bounds__(256) void prep_x(
    const float* __restrict__ x, f16* __restrict__ Xh, f16* __restrict__ Xl)
{
    int idx = blockIdx.x * 256 + threadIdx.x;
    float4 v = ((const float4*)x)[idx];
    f16x4 h, l;
    h.x = (f16)v.x; l.x = (f16)(v.x - (float)h.x);
    h.y = (f16)v.y; l.y = (f16)(v.y - (float)h.y);
    h.z = (f16)v.z; l.z = (f16)(v.z - (float)h.z);
    h.w = (f16)v.w; l.w = (f16)(v.w - (float)h.w);
    ((f16x4*)Xh)[idx] = h;
    ((f16x4*)Xl)[idx] = l;
}

// ---------------------------------------------------------------------------
// Kernel 1: fuse weights W' = W_embed @ W (fp32 math), output TRANSPOSED
// fp16 split:  Wth/Wtl [z][n=512][k=256]
// ---------------------------------------------------------------------------
__global__ __launch_bounds__(256) void fuse_weights(
    const float* __restrict__ We, const float* __restrict__ Wk,
    const float* __restrict__ Wq, const float* __restrict__ Wv,
    f16* __restrict__ Wth, f16* __restrict__ Wtl)
{
    int idx = blockIdx.x * 256 + threadIdx.x;
    int n = idx & 511;
    int m = (idx >> 9) & 255;
    int z = idx >> 17;
    const float* Wsrc = (z == 0) ? Wk : (z == 1) ? Wq : Wv;
    float sum = 0.f;
#pragma unroll 8
    for (int kk = 0; kk < DEMB; ++kk)
        sum += We[m * DEMB + kk] * Wsrc[kk * 512 + n];
    f16 h = (f16)sum;
    f16 l = (f16)(sum - (float)h);
    Wth[(size_t)z * 131072 + n * 256 + m] = h;
    Wtl[(size_t)z * 131072 + n * 256 + m] = l;
}

// ---------------------------------------------------------------------------
// Kernel 2: MFMA projections, 3-term fp16 split (Ah*Bh + Al*Bh + Ah*Bl).
// Tile 128x128, K-chunk 64, 4 waves. global_load_lds staging.
//   z=0 -> Kh [row][512]; z=1 -> Qh [row][512];
//   z=2 -> Vt2 [b][tile(64)][dv(512)][32 keys], 16B slots permuted by vperm(dv)
// ---------------------------------------------------------------------------
#define QAH 0
#define QAL 8192
#define QBH 16384
#define QBL 24576

__global__ __launch_bounds__(256) void qkv_gemm(
    const f16* __restrict__ Xh, const f16* __restrict__ Xl,
    const f16* __restrict__ Wth, const f16* __restrict__ Wtl,
    f16* __restrict__ Kh, f16* __restrict__ Qh, f16* __restrict__ Vt2)
{
    __shared__ __align__(16) short smq[32768];   // 64 KB

    const int tid  = threadIdx.x;
    const int lane = tid & 63;
    const int w    = tid >> 6;
    const int z    = blockIdx.z;
    const int m0   = blockIdx.y * 128;
    const int n0   = blockIdx.x * 128;
    const int l15  = lane & 15;
    const int quad = lane >> 4;
    const int wm   = (w >> 1) * 64, wn = (w & 1) * 64;

    const f16* Bh = Wth + (size_t)z * 131072;
    const f16* Bl = Wtl + (size_t)z * 131072;

    f32x4 acc[4][4];
#pragma unroll
    for (int i = 0; i < 4; ++i)
#pragma unroll
        for (int j = 0; j < 4; ++j) acc[i][j] = (f32x4){0.f, 0.f, 0.f, 0.f};

    const int lrow = lane >> 3;
    const int lswz = ((lane & 7) ^ (lrow & 7)) << 3;

    for (int c = 0; c < 4; ++c) {
        const int k0 = c * 64;
#pragma unroll
        for (int i = 0; i < 4; ++i) {
            int r0 = w * 32 + i * 8;
            int row = r0 + lrow;
            GLOAD_LDS16(Xh + (size_t)(m0 + row) * 256 + k0 + lswz, smq + QAH + r0 * 64);
            GLOAD_LDS16(Xl + (size_t)(m0 + row) * 256 + k0 + lswz, smq + QAL + r0 * 64);
            GLOAD_LDS16(Bh + (size_t)(n0 + row) * 256 + k0 + lswz, smq + QBH + r0 * 64);
            GLOAD_LDS16(Bl + (size_t)(n0 + row) * 256 + k0 + lswz, smq + QBL + r0 * 64);
        }
        __syncthreads();
#pragma unroll
        for (int ks = 0; ks < 2; ++ks) {
            const int kg = ks * 4 + quad;
            const int rsw = (kg ^ (l15 & 7)) << 3;
            half8 ah[4], al[4], bh[4], bl[4];
#pragma unroll
            for (int i = 0; i < 4; ++i) {
                int m = wm + i * 16 + l15;
                int n = wn + i * 16 + l15;
                ah[i] = *(const half8*)(smq + QAH + m * 64 + rsw);
                al[i] = *(const half8*)(smq + QAL + m * 64 + rsw);
                bh[i] = *(const half8*)(smq + QBH + n * 64 + rsw);
                bl[i] = *(const half8*)(smq + QBL + n * 64 + rsw);
            }
#pragma unroll
            for (int mi = 0; mi < 4; ++mi)
#pragma unroll
                for (int ni = 0; ni < 4; ++ni) {
                    acc[mi][ni] = __builtin_amdgcn_mfma_f32_16x16x32_f16(ah[mi], bh[ni], acc[mi][ni], 0, 0, 0);
                    acc[mi][ni] = __builtin_amdgcn_mfma_f32_16x16x32_f16(al[mi], bh[ni], acc[mi][ni], 0, 0, 0);
                    acc[mi][ni] = __builtin_amdgcn_mfma_f32_16x16x32_f16(ah[mi], bl[ni], acc[mi][ni], 0, 0, 0);
                }
        }
        __syncthreads();
    }

    // ---- epilogue via LDS (stride 136 shorts) ----
    if (z < 2) {
#pragma unroll
        for (int mi = 0; mi < 4; ++mi)
#pragma unroll
            for (int ni = 0; ni < 4; ++ni)
#pragma unroll
                for (int r = 0; r < 4; ++r)
                    *(f16*)(smq + (wm + mi * 16 + quad * 4 + r) * 136 + wn + ni * 16 + l15) =
                        (f16)acc[mi][ni][r];
        __syncthreads();
        f16* Out = (z == 0) ? Kh : Qh;
        int cg = tid & 15;
#pragma unroll
        for (int j = 0; j < 8; ++j) {
            int row = j * 16 + (tid >> 4);
            half8 v = *(const half8*)(smq + row * 136 + cg * 8);
            *(half8*)&Out[(size_t)(m0 + row) * 512 + n0 + cg * 8] = v;
        }
    } else {
        // transpose in LDS: [dv_local][key_local]
#pragma unroll
        for (int mi = 0; mi < 4; ++mi)
#pragma unroll
            for (int ni = 0; ni < 4; ++ni)
#pragma unroll
                for (int r = 0; r < 4; ++r)
                    *(f16*)(smq + (wn + ni * 16 + l15) * 136 + wm + mi * 16 + quad * 4 + r) =
                        (f16)acc[mi][ni][r];
        __syncthreads();
        int bb = m0 >> 11, kb0 = m0 & 2047;
        int cg = tid & 15;
#pragma unroll
        for (int j = 0; j < 8; ++j) {
            int dvr = j * 16 + (tid >> 4);
            int dv  = n0 + dvr;
            half8 v = *(const half8*)(smq + dvr * 136 + cg * 8);
            int t  = (kb0 >> 5) + (cg >> 2);     // key tile
            int s  = (cg & 3) ^ vperm(dv);       // permuted 16B slot
            *(half8*)&Vt2[(((size_t)bb * 64 + t) * 512 + dv) * 32 + s * 8] = v;
        }
    }
}

// ---------------------------------------------------------------------------
// Kernel 3: MFMA flash attention — ONE barrier per tile.
// 8 waves, 128 q rows, grid 256 (1 block/CU). K,V,P,alpha,flags all double-
// buffered (153.2 KB LDS). Interval t (between barriers B(t-1) and Bt):
//   issue stage_K(t+1)->K[nxt], stage_V(t)->V[cur]   (use is next interval)
//   PV(t-1): rescale(prv) + 16x 32x32 MFMA  (P[prv], V[prv])
//   scores(t): 32x 16x16 MFMA               (K[cur])
//   softmax(t) -> P[cur], alpha[cur], flags[cur]
//   s_waitcnt vmcnt(0) lgkmcnt(0); s_barrier
// 48 MFMAs back-to-back per interval per wave restores intra-wave latency
// hiding that R1's 2-barrier lockstep destroyed; prefetch windows = full
// interval; staging traffic stays halved vs the 2-block version.
// ---------------------------------------------------------------------------
#define LKA 0        // K buf0: 32 keys x 512 d   = 16384 shorts
#define LKB 16384    // K buf1
#define LVA 32768    // V buf0: 512 dv x 32 keys  = 16384 shorts
#define LVB 49152    // V buf1
#define LPA 65536    // P buf0: 128 q x stride 40 =  5120 shorts
#define LPB 70656    // P buf1
#define LAA 75776    // alpha buf0/buf1: 2 x 128 floats = 512 shorts
#define LLL 76288    // l[128] floats             =   256 shorts
#define LFA 76544    // flags buf0/buf1: 2 x 8 ints = 32 shorts
#define LTOT 76576   // 153152 bytes (< 160 KiB)

#define RESCALE_THR 8.0f

__global__ __launch_bounds__(512, 2) void attn2(
    const f16* __restrict__ Qh, const f16* __restrict__ Kh,
    const f16* __restrict__ Vt2, float* __restrict__ Y)
{
    __shared__ __align__(16) short sm[LTOT];

    const int tid  = threadIdx.x;
    const int lane = tid & 63;
    const int w    = tid >> 6;                    // 0..7
    // XCD-aware decode: xcd = gid&7; b = (gid&7) + 8*(gid>>7); q0 = ((gid>>3)&15)*128
    const int gid  = blockIdx.x;
    const int b    = (gid & 7) + ((gid >> 7) << 3);
    const int q0   = ((gid >> 3) & 15) << 7;
    const int l15  = lane & 15;
    const int quad = lane >> 4;
    const int l31  = lane & 31;
    const int lhi  = lane >> 5;
    const int qquad = w >> 1, dvhalf = w & 1;     // PV mapping: 4 q-quads x 2 dv-halves

    const f16* Khb  = Kh  + (size_t)b * SS * 512;
    const f16* Vt2b = Vt2 + (size_t)b * 64 * 512 * 32;

    // ---- Q fragments (resident): wave w, q rows q0+16w .. +15 ----
    half8 qh[16];
    {
        const half8* qhp = (const half8*)(Qh + ((size_t)(b * SS + q0 + w * 16 + l15)) * 512);
#pragma unroll
        for (int ks = 0; ks < 16; ++ks) qh[ks] = qhp[ks * 4 + quad];
    }

    f32x16 O[8];
#pragma unroll
    for (int n = 0; n < 8; ++n)
#pragma unroll
        for (int r = 0; r < 16; ++r) O[n][r] = 0.f;

    float m_pr[4] = {-1e30f, -1e30f, -1e30f, -1e30f};
    float l_r[4]  = {0.f, 0.f, 0.f, 0.f};

    // 8 waves x 4 instrs = 32 KB per tile for each of K and V
    auto stage_K = [&](int t, int lk) {
        const int kb = t * 32;
#pragma unroll
        for (int i = 0; i < 4; ++i) {
            int key = w * 4 + i;
            const f16* g = Khb + ((size_t)(kb + key)) * 512 + ((lane ^ (key & 15)) << 3);
            GLOAD_LDS16(g, sm + lk + key * 512);
        }
    };
    auto stage_V = [&](int t, int lv) {
        const f16* gbase = Vt2b + (size_t)t * 16384 + lane * 8;
#pragma unroll
        for (int i = 0; i < 4; ++i) {
            int off = (w * 4 + i) * 512;
            GLOAD_LDS16(gbase + off, sm + lv + off);
        }
    };

    // ---- PV(tp): rescale O by alpha(tp) then O += P(tp) * V(tp) ----
    auto do_pv = [&](int LPp, int LVp, const float* ap, const int* fp) {
        if (fp[2 * qquad] | fp[2 * qquad + 1]) {
            float av[16];
#pragma unroll
            for (int r = 0; r < 16; ++r) {
                int row = (r & 3) + ((r >> 2) << 3) + (lhi << 2);
                av[r] = ap[qquad * 32 + row];
            }
#pragma unroll
            for (int n = 0; n < 8; ++n)
#pragma unroll
                for (int r = 0; r < 16; ++r) O[n][r] *= av[r];
        }
        half8 pA[2];
#pragma unroll
        for (int ks = 0; ks < 2; ++ks) {
            int q  = qquad * 32 + l31;
            int uk = ks * 2 + lhi;
            pA[ks] = *(const half8*)(sm + LPp + q * 40 + uk * 8);
        }
#pragma unroll
        for (int ks = 0; ks < 2; ++ks) {
#pragma unroll
            for (int n = 0; n < 8; ++n) {
                int dv = dvhalf * 256 + n * 32 + l31;
                int uk = ks * 2 + lhi;
                half8 bf = *(const half8*)(sm + LVp + dv * 32 + ((uk ^ vperm(dv)) << 3));
                O[n] = __builtin_amdgcn_mfma_f32_32x32x16_f16(pA[ks], bf, O[n], 0, 0, 0);
            }
        }
    };

    // ---- prologue: stage K(0) into buf0, sync ----
    stage_K(0, LKA);
    asm volatile("s_waitcnt vmcnt(0)" ::: "memory");
    __builtin_amdgcn_s_barrier();
    __builtin_amdgcn_sched_barrier(0);

    for (int t = 0; t < 64; ++t) {
        const int cur = t & 1;
        const int prv = cur ^ 1;
        const int LKc = LKA + cur * 16384;   // K(t)
        const int LKn = LKA + prv * 16384;   // K(t+1) dest
        const int LVc = LVA + cur * 16384;   // V(t) dest
        const int LVp = LVA + prv * 16384;   // V(t-1)
        const int LPc = LPA + cur * 5120;    // P(t) dest
        const int LPp = LPA + prv * 5120;    // P(t-1)
        float* aw = (float*)(sm + LAA + cur * 256);
        const float* ap = (const float*)(sm + LAA + prv * 256);
        int* fw = (int*)(sm + LFA + cur * 16);
        const int* fp = (const int*)(sm + LFA + prv * 16);

        // prefetch: K(t+1) and V(t); both consumed NEXT interval
        if (t + 1 < 64) stage_K(t + 1, LKn);
        stage_V(t, LVc);

        __builtin_amdgcn_s_setprio(1);
        // ---- PV(t-1) ----
        if (t > 0) do_pv(LPp, LVp, ap, fp);

        // ---- scores(t): S = Qh * Kh^T (16x16x32), 16 q x 32 keys per wave ----
        f32x4 S[2];
        S[0] = (f32x4){0.f, 0.f, 0.f, 0.f};
        S[1] = (f32x4){0.f, 0.f, 0.f, 0.f};
#pragma unroll
        for (int ks = 0; ks < 16; ++ks) {
#pragma unroll
            for (int n = 0; n < 2; ++n) {
                int key = n * 16 + l15;
                int ud  = ks * 4 + quad;
                half8 bf = *(const half8*)(sm + LKc + key * 512 + ((ud ^ l15) << 3));
                S[n] = __builtin_amdgcn_mfma_f32_16x16x32_f16(qh[ks], bf, S[n], 0, 0, 0);
            }
        }
        __builtin_amdgcn_s_setprio(0);

        // ---- online softmax with defer-max (THR=8) ----
        float mx[4], sum[4], al[4];
#pragma unroll
        for (int r = 0; r < 4; ++r) mx[r] = fmaxf(S[0][r], S[1][r]);
#pragma unroll
        for (int off = 1; off < 16; off <<= 1)
#pragma unroll
            for (int r = 0; r < 4; ++r)
                mx[r] = fmaxf(mx[r], __shfl_xor(mx[r], off, 64));
#pragma unroll
        for (int r = 0; r < 4; ++r) {
            bool up  = mx[r] > m_pr[r] + RESCALE_THR;   // defer small max growth
            float mn = up ? mx[r] : m_pr[r];
            al[r]    = up ? __expf(m_pr[r] - mn) : 1.0f;
            m_pr[r]  = mn;
            sum[r]   = 0.f;
        }
#pragma unroll
        for (int n = 0; n < 2; ++n) {
#pragma unroll
            for (int r = 0; r < 4; ++r) {
                float p = __expf(S[n][r] - m_pr[r]);    // bounded by e^THR
                sum[r] += p;
                int q   = w * 16 + quad * 4 + r;
                int key = n * 16 + l15;
                *(f16*)(sm + LPc + q * 40 + key) = (f16)p;
            }
        }
#pragma unroll
        for (int off = 1; off < 16; off <<= 1)
#pragma unroll
            for (int r = 0; r < 4; ++r)
                sum[r] += __shfl_xor(sum[r], off, 64);
#pragma unroll
        for (int r = 0; r < 4; ++r)
            l_r[r] = l_r[r] * al[r] + sum[r];
        bool any = (al[0] < 1.f) | (al[1] < 1.f) | (al[2] < 1.f) | (al[3] < 1.f);
        unsigned long long bm = __ballot(any);
        if (lane == 0) fw[w] = (bm != 0ULL) ? 1 : 0;
        if (l15 == 0) {
#pragma unroll
            for (int r = 0; r < 4; ++r) aw[w * 16 + quad * 4 + r] = al[r];
        }

        // ---- single barrier: P/alpha/flags(t) visible; K(t+1)/V(t) landed ----
        asm volatile("s_waitcnt vmcnt(0) lgkmcnt(0)" ::: "memory");
        __builtin_amdgcn_s_barrier();
        __builtin_amdgcn_sched_barrier(0);
    }

    // ---- final PV(63) (buffers at parity of t=63 -> cur=1) ----
    do_pv(LPA + 5120, LVA + 16384,
          (const float*)(sm + LAA + 256), (const int*)(sm + LFA + 16));

    // ---- epilogue: O /= l, store ----
    float* lptr = (float*)(sm + LLL);
    if (l15 == 0) {
#pragma unroll
        for (int r = 0; r < 4; ++r) lptr[w * 16 + quad * 4 + r] = l_r[r];
    }
    __syncthreads();
    float linv[16];
#pragma unroll
    for (int r = 0; r < 16; ++r) {
        int row = (r & 3) + ((r >> 2) << 3) + (lhi << 2);
        linv[r] = 1.0f / lptr[qquad * 32 + row];
    }
#pragma unroll
    for (int n = 0; n < 8; ++n) {
#pragma unroll
        for (int r = 0; r < 16; ++r) {
            int row = (r & 3) + ((r >> 2) << 3) + (lhi << 2);
            Y[((size_t)(b * SS + q0 + qquad * 32 + row)) * 512 + dvhalf * 256 + n * 32 + l31] =
                O[n][r] * linv[r];
        }
    }
}

// ---------------------------------------------------------------------------
// Host launcher
// ---------------------------------------------------------------------------
extern "C" void kernel_launch(void* const* d_in, const int* in_sizes, int n_in,
                              void* d_out, int out_size, void* d_ws, size_t ws_size,
                              hipStream_t stream)
{
    const float* x  = (const float*)d_in[0];
    const float* We = (const float*)d_in[1];
    const float* Wk = (const float*)d_in[2];
    const float* Wq = (const float*)d_in[3];
    const float* Wv = (const float*)d_in[4];
    float* out = (float*)d_out;

    const size_t WSZ = 3 * 256 * 512;          // 393216
    const size_t XSZ = (size_t)BB * SS * DIN;  // 8388608
    const size_t MSZ = (size_t)BB * SS * 512;  // 16777216

    f16* Wth = (f16*)d_ws;
    f16* Wtl = Wth + WSZ;
    f16* Xh  = Wtl + WSZ;
    f16* Xl  = Xh + XSZ;
    f16* Qh  = Xl + XSZ;
    f16* Kh  = Qh + MSZ;
    f16* Vt2 = Kh + MSZ;

    prep_x<<<dim3(XSZ / 4 / 256), dim3(256), 0, stream>>>(x, Xh, Xl);

    fuse_weights<<<dim3(1536), dim3(256), 0, stream>>>(We, Wk, Wq, Wv, Wth, Wtl);

    qkv_gemm<<<dim3(4, 256, 3), dim3(256), 0, stream>>>(
        Xh, Xl, Wth, Wtl, Kh, Qh, Vt2);

    attn2<<<dim3(256), dim3(512), 0, stream>>>(Qh, Kh, Vt2, out);
}

// Round 3
// 468.217 us; speedup vs baseline: 1.4642x; 1.3244x over previous
//
#include <hip/hip_runtime.h>
#include <math.h>

// Problem dims (fixed)
#define BB   16
#define SS   2048
#define DIN  256
#define DEMB 512
#define DKQ  512
#define DVV  512

typedef _Float16 f16;
typedef _Float16 half8  __attribute__((ext_vector_type(8)));
typedef _Float16 f16x4  __attribute__((ext_vector_type(4)));
typedef float    f32x4  __attribute__((ext_vector_type(4)));
typedef float    f32x16 __attribute__((ext_vector_type(16)));

#define GLOAD_LDS16(gp, lp)                                                        \
  __builtin_amdgcn_global_load_lds(                                                \
      (const __attribute__((address_space(1))) unsigned int*)(gp),                 \
      (__attribute__((address_space(3))) unsigned int*)(lp), 16, 0, 0)

// V slot permute: decorrelates LDS bank-start across dv rows (2-way max)
__device__ __forceinline__ int vperm(int dv) { return (dv ^ (dv >> 2)) & 3; }

// ---------------------------------------------------------------------------
// Kernel 0: split x (fp32) -> Xh, Xl (fp16 pair, exact to ~2^-22)
// ---------------------------------------------------------------------------
__global__ __launch_bounds__(256) void prep_x(
    const float* __restrict__ x, f16* __restrict__ Xh, f16* __restrict__ Xl)
{
    int idx = blockIdx.x * 256 + threadIdx.x;
    float4 v = ((const float4*)x)[idx];
    f16x4 h, l;
    h.x = (f16)v.x; l.x = (f16)(v.x - (float)h.x);
    h.y = (f16)v.y; l.y = (f16)(v.y - (float)h.y);
    h.z = (f16)v.z; l.z = (f16)(v.z - (float)h.z);
    h.w = (f16)v.w; l.w = (f16)(v.w - (float)h.w);
    ((f16x4*)Xh)[idx] = h;
    ((f16x4*)Xl)[idx] = l;
}

// ---------------------------------------------------------------------------
// Kernel 1: fuse weights W' = W_embed @ W (fp32 math), output TRANSPOSED
// fp16 split:  Wth/Wtl [z][n=512][k=256]
// ---------------------------------------------------------------------------
__global__ __launch_bounds__(256) void fuse_weights(
    const float* __restrict__ We, const float* __restrict__ Wk,
    const float* __restrict__ Wq, const float* __restrict__ Wv,
    f16* __restrict__ Wth, f16* __restrict__ Wtl)
{
    int idx = blockIdx.x * 256 + threadIdx.x;
    int n = idx & 511;
    int m = (idx >> 9) & 255;
    int z = idx >> 17;
    const float* Wsrc = (z == 0) ? Wk : (z == 1) ? Wq : Wv;
    float sum = 0.f;
#pragma unroll 8
    for (int kk = 0; kk < DEMB; ++kk)
        sum += We[m * DEMB + kk] * Wsrc[kk * 512 + n];
    f16 h = (f16)sum;
    f16 l = (f16)(sum - (float)h);
    Wth[(size_t)z * 131072 + n * 256 + m] = h;
    Wtl[(size_t)z * 131072 + n * 256 + m] = l;
}

// ---------------------------------------------------------------------------
// Kernel 2: MFMA projections, 3-term fp16 split (Ah*Bh + Al*Bh + Ah*Bl).
// Tile 128x128, K-chunk 64, 4 waves. global_load_lds staging.
//   z=0 -> Kh [row][512]; z=1 -> Qh [row][512] PRE-SCALED by log2(e);
//   z=2 -> Vt2 [b][tile(64)][dv(512)][32 keys], 16B slots permuted by vperm(dv)
// ---------------------------------------------------------------------------
#define QAH 0
#define QAL 8192
#define QBH 16384
#define QBL 24576

__global__ __launch_bounds__(256) void qkv_gemm(
    const f16* __restrict__ Xh, const f16* __restrict__ Xl,
    const f16* __restrict__ Wth, const f16* __restrict__ Wtl,
    f16* __restrict__ Kh, f16* __restrict__ Qh, f16* __restrict__ Vt2)
{
    __shared__ __align__(16) short smq[32768];   // 64 KB

    const int tid  = threadIdx.x;
    const int lane = tid & 63;
    const int w    = tid >> 6;
    const int z    = blockIdx.z;
    const int m0   = blockIdx.y * 128;
    const int n0   = blockIdx.x * 128;
    const int l15  = lane & 15;
    const int quad = lane >> 4;
    const int wm   = (w >> 1) * 64, wn = (w & 1) * 64;

    const f16* Bh = Wth + (size_t)z * 131072;
    const f16* Bl = Wtl + (size_t)z * 131072;

    f32x4 acc[4][4];
#pragma unroll
    for (int i = 0; i < 4; ++i)
#pragma unroll
        for (int j = 0; j < 4; ++j) acc[i][j] = (f32x4){0.f, 0.f, 0.f, 0.f};

    const int lrow = lane >> 3;
    const int lswz = ((lane & 7) ^ (lrow & 7)) << 3;

    for (int c = 0; c < 4; ++c) {
        const int k0 = c * 64;
#pragma unroll
        for (int i = 0; i < 4; ++i) {
            int r0 = w * 32 + i * 8;
            int row = r0 + lrow;
            GLOAD_LDS16(Xh + (size_t)(m0 + row) * 256 + k0 + lswz, smq + QAH + r0 * 64);
            GLOAD_LDS16(Xl + (size_t)(m0 + row) * 256 + k0 + lswz, smq + QAL + r0 * 64);
            GLOAD_LDS16(Bh + (size_t)(n0 + row) * 256 + k0 + lswz, smq + QBH + r0 * 64);
            GLOAD_LDS16(Bl + (size_t)(n0 + row) * 256 + k0 + lswz, smq + QBL + r0 * 64);
        }
        __syncthreads();
#pragma unroll
        for (int ks = 0; ks < 2; ++ks) {
            const int kg = ks * 4 + quad;
            const int rsw = (kg ^ (l15 & 7)) << 3;
            half8 ah[4], al[4], bh[4], bl[4];
#pragma unroll
            for (int i = 0; i < 4; ++i) {
                int m = wm + i * 16 + l15;
                int n = wn + i * 16 + l15;
                ah[i] = *(const half8*)(smq + QAH + m * 64 + rsw);
                al[i] = *(const half8*)(smq + QAL + m * 64 + rsw);
                bh[i] = *(const half8*)(smq + QBH + n * 64 + rsw);
                bl[i] = *(const half8*)(smq + QBL + n * 64 + rsw);
            }
#pragma unroll
            for (int mi = 0; mi < 4; ++mi)
#pragma unroll
                for (int ni = 0; ni < 4; ++ni) {
                    acc[mi][ni] = __builtin_amdgcn_mfma_f32_16x16x32_f16(ah[mi], bh[ni], acc[mi][ni], 0, 0, 0);
                    acc[mi][ni] = __builtin_amdgcn_mfma_f32_16x16x32_f16(al[mi], bh[ni], acc[mi][ni], 0, 0, 0);
                    acc[mi][ni] = __builtin_amdgcn_mfma_f32_16x16x32_f16(ah[mi], bl[ni], acc[mi][ni], 0, 0, 0);
                }
        }
        __syncthreads();
    }

    // ---- epilogue via LDS (stride 136 shorts) ----
    if (z < 2) {
        // Q (z==1) is pre-scaled by log2(e) so attention can use raw exp2.
        const float qsc = (z == 1) ? 1.44269504f : 1.0f;
#pragma unroll
        for (int mi = 0; mi < 4; ++mi)
#pragma unroll
            for (int ni = 0; ni < 4; ++ni)
#pragma unroll
                for (int r = 0; r < 4; ++r)
                    *(f16*)(smq + (wm + mi * 16 + quad * 4 + r) * 136 + wn + ni * 16 + l15) =
                        (f16)(acc[mi][ni][r] * qsc);
        __syncthreads();
        f16* Out = (z == 0) ? Kh : Qh;
        int cg = tid & 15;
#pragma unroll
        for (int j = 0; j < 8; ++j) {
            int row = j * 16 + (tid >> 4);
            half8 v = *(const half8*)(smq + row * 136 + cg * 8);
            *(half8*)&Out[(size_t)(m0 + row) * 512 + n0 + cg * 8] = v;
        }
    } else {
        // transpose in LDS: [dv_local][key_local]
#pragma unroll
        for (int mi = 0; mi < 4; ++mi)
#pragma unroll
            for (int ni = 0; ni < 4; ++ni)
#pragma unroll
                for (int r = 0; r < 4; ++r)
                    *(f16*)(smq + (wn + ni * 16 + l15) * 136 + wm + mi * 16 + quad * 4 + r) =
                        (f16)acc[mi][ni][r];
        __syncthreads();
        int bb = m0 >> 11, kb0 = m0 & 2047;
        int cg = tid & 15;
#pragma unroll
        for (int j = 0; j < 8; ++j) {
            int dvr = j * 16 + (tid >> 4);
            int dv  = n0 + dvr;
            half8 v = *(const half8*)(smq + dvr * 136 + cg * 8);
            int t  = (kb0 >> 5) + (cg >> 2);     // key tile
            int s  = (cg & 3) ^ vperm(dv);       // permuted 16B slot
            *(half8*)&Vt2[(((size_t)bb * 64 + t) * 512 + dv) * 32 + s * 8] = v;
        }
    }
}

// ---------------------------------------------------------------------------
// Kernel 3: MFMA flash attention — ONE barrier per tile (R2 schedule kept),
// SWAPPED-OPERAND scores + lane-local softmax (DS-pipe diet).
// S^T = mfma(K_frag, Q_frag): identical LDS reads as before, but output is
// [key][q]: lane holds 8 keys for ONE q row (q = w*16+l15). Softmax row-
// reduce = local tree + 2 shuffles (was 32 shuffles/wave); P written as
// 2x ds_write_b64 (was 8x ds_write_u16); m/l are per-lane scalars.
// Softmax in log2 domain (Qh pre-scaled by log2e) -> raw v_exp_f32.
// PV (32x32x16), staging, dbuf, barrier structure unchanged from R2.
// ---------------------------------------------------------------------------
#define LKA 0        // K buf0: 32 keys x 512 d   = 16384 shorts
#define LKB 16384    // K buf1
#define LVA 32768    // V buf0: 512 dv x 32 keys  = 16384 shorts
#define LVB 49152    // V buf1
#define LPA 65536    // P buf0: 128 q x stride 40 =  5120 shorts
#define LPB 70656    // P buf1
#define LAA 75776    // alpha buf0/buf1: 2 x 128 floats = 512 shorts
#define LLL 76288    // l[128] floats             =   256 shorts
#define LFA 76544    // flags buf0/buf1: 2 x 8 ints = 32 shorts
#define LTOT 76576   // 153152 bytes (< 160 KiB)

#define THR_L2 11.5416f   // defer-max threshold: 8 nats in log2 units

__global__ __launch_bounds__(512, 2) void attn2(
    const f16* __restrict__ Qh, const f16* __restrict__ Kh,
    const f16* __restrict__ Vt2, float* __restrict__ Y)
{
    __shared__ __align__(16) short sm[LTOT];

    const int tid  = threadIdx.x;
    const int lane = tid & 63;
    const int w    = tid >> 6;                    // 0..7
    // XCD-aware decode: xcd = gid&7; b = (gid&7) + 8*(gid>>7); q0 = ((gid>>3)&15)*128
    const int gid  = blockIdx.x;
    const int b    = (gid & 7) + ((gid >> 7) << 3);
    const int q0   = ((gid >> 3) & 15) << 7;
    const int l15  = lane & 15;
    const int quad = lane >> 4;
    const int l31  = lane & 31;
    const int lhi  = lane >> 5;
    const int qquad = w >> 1, dvhalf = w & 1;     // PV mapping: 4 q-quads x 2 dv-halves

    const f16* Khb  = Kh  + (size_t)b * SS * 512;
    const f16* Vt2b = Vt2 + (size_t)b * 64 * 512 * 32;

    // ---- Q fragments (resident): wave w, q rows q0+16w .. +15 ----
    half8 qh[16];
    {
        const half8* qhp = (const half8*)(Qh + ((size_t)(b * SS + q0 + w * 16 + l15)) * 512);
#pragma unroll
        for (int ks = 0; ks < 16; ++ks) qh[ks] = qhp[ks * 4 + quad];
    }

    f32x16 O[8];
#pragma unroll
    for (int n = 0; n < 8; ++n)
#pragma unroll
        for (int r = 0; r < 16; ++r) O[n][r] = 0.f;

    float m_pr = -1e30f;   // running max, log2 domain (per lane's q row)
    float l_r  = 0.f;      // running denom (per lane's q row)

    // 8 waves x 4 instrs = 32 KB per tile for each of K and V
    auto stage_K = [&](int t, int lk) {
        const int kb = t * 32;
#pragma unroll
        for (int i = 0; i < 4; ++i) {
            int key = w * 4 + i;
            const f16* g = Khb + ((size_t)(kb + key)) * 512 + ((lane ^ (key & 15)) << 3);
            GLOAD_LDS16(g, sm + lk + key * 512);
        }
    };
    auto stage_V = [&](int t, int lv) {
        const f16* gbase = Vt2b + (size_t)t * 16384 + lane * 8;
#pragma unroll
        for (int i = 0; i < 4; ++i) {
            int off = (w * 4 + i) * 512;
            GLOAD_LDS16(gbase + off, sm + lv + off);
        }
    };

    // ---- PV(tp): rescale O by alpha(tp) then O += P(tp) * V(tp) ----
    auto do_pv = [&](int LPp, int LVp, const float* ap, const int* fp) {
        if (fp[2 * qquad] | fp[2 * qquad + 1]) {
            float av[16];
#pragma unroll
            for (int r = 0; r < 16; ++r) {
                int row = (r & 3) + ((r >> 2) << 3) + (lhi << 2);
                av[r] = ap[qquad * 32 + row];
            }
#pragma unroll
            for (int n = 0; n < 8; ++n)
#pragma unroll
                for (int r = 0; r < 16; ++r) O[n][r] *= av[r];
        }
        half8 pA[2];
#pragma unroll
        for (int ks = 0; ks < 2; ++ks) {
            int q  = qquad * 32 + l31;
            int uk = ks * 2 + lhi;
            pA[ks] = *(const half8*)(sm + LPp + q * 40 + uk * 8);
        }
#pragma unroll
        for (int ks = 0; ks < 2; ++ks) {
#pragma unroll
            for (int n = 0; n < 8; ++n) {
                int dv = dvhalf * 256 + n * 32 + l31;
                int uk = ks * 2 + lhi;
                half8 bf = *(const half8*)(sm + LVp + dv * 32 + ((uk ^ vperm(dv)) << 3));
                O[n] = __builtin_amdgcn_mfma_f32_32x32x16_f16(pA[ks], bf, O[n], 0, 0, 0);
            }
        }
    };

    // ---- prologue: stage K(0) into buf0, sync ----
    stage_K(0, LKA);
    asm volatile("s_waitcnt vmcnt(0)" ::: "memory");
    __builtin_amdgcn_s_barrier();
    __builtin_amdgcn_sched_barrier(0);

    for (int t = 0; t < 64; ++t) {
        const int cur = t & 1;
        const int prv = cur ^ 1;
        const int LKc = LKA + cur * 16384;   // K(t)
        const int LKn = LKA + prv * 16384;   // K(t+1) dest
        const int LVc = LVA + cur * 16384;   // V(t) dest
        const int LVp = LVA + prv * 16384;   // V(t-1)
        const int LPc = LPA + cur * 5120;    // P(t) dest
        const int LPp = LPA + prv * 5120;    // P(t-1)
        float* aw = (float*)(sm + LAA + cur * 256);
        const float* ap = (const float*)(sm + LAA + prv * 256);
        int* fw = (int*)(sm + LFA + cur * 16);
        const int* fp = (const int*)(sm + LFA + prv * 16);

        // prefetch: K(t+1) and V(t); both consumed NEXT interval
        if (t + 1 < 64) stage_K(t + 1, LKn);
        stage_V(t, LVc);

        __builtin_amdgcn_s_setprio(1);
        // ---- PV(t-1) ----
        if (t > 0) do_pv(LPp, LVp, ap, fp);

        // ---- scores(t), SWAPPED: S^T = K * Q^T (16x16x32) ----
        // A = K frag (identical LDS addresses as before), B = qh (resident).
        // C: col=l15=q, row=quad*4+r = key (within n*16 block).
        f32x4 S[2];
        S[0] = (f32x4){0.f, 0.f, 0.f, 0.f};
        S[1] = (f32x4){0.f, 0.f, 0.f, 0.f};
#pragma unroll
        for (int ks = 0; ks < 16; ++ks) {
#pragma unroll
            for (int n = 0; n < 2; ++n) {
                int key = n * 16 + l15;
                int ud  = ks * 4 + quad;
                half8 bf = *(const half8*)(sm + LKc + key * 512 + ((ud ^ l15) << 3));
                S[n] = __builtin_amdgcn_mfma_f32_16x16x32_f16(bf, qh[ks], S[n], 0, 0, 0);
            }
        }
        __builtin_amdgcn_s_setprio(0);

        // ---- lane-local online softmax (log2 domain), defer-max ----
        // lane's q row: q = w*16 + l15; lane's 8 keys: n*16 + quad*4 + r
        float mx = fmaxf(fmaxf(fmaxf(S[0][0], S[0][1]), fmaxf(S[0][2], S[0][3])),
                         fmaxf(fmaxf(S[1][0], S[1][1]), fmaxf(S[1][2], S[1][3])));
        mx = fmaxf(mx, __shfl_xor(mx, 16, 64));
        mx = fmaxf(mx, __shfl_xor(mx, 32, 64));
        bool up  = mx > m_pr + THR_L2;          // defer small max growth
        float mn = up ? mx : m_pr;
        float al = up ? __builtin_amdgcn_exp2f(m_pr - mn) : 1.0f;
        m_pr = mn;

        float p0 = __builtin_amdgcn_exp2f(S[0][0] - mn);
        float p1 = __builtin_amdgcn_exp2f(S[0][1] - mn);
        float p2 = __builtin_amdgcn_exp2f(S[0][2] - mn);
        float p3 = __builtin_amdgcn_exp2f(S[0][3] - mn);
        float p4 = __builtin_amdgcn_exp2f(S[1][0] - mn);
        float p5 = __builtin_amdgcn_exp2f(S[1][1] - mn);
        float p6 = __builtin_amdgcn_exp2f(S[1][2] - mn);
        float p7 = __builtin_amdgcn_exp2f(S[1][3] - mn);
        float sum = ((p0 + p1) + (p2 + p3)) + ((p4 + p5) + (p6 + p7));
        sum += __shfl_xor(sum, 16, 64);
        sum += __shfl_xor(sum, 32, 64);
        l_r = l_r * al + sum;

        {
            int q = w * 16 + l15;
            f16x4 lo, hi;
            lo.x = (f16)p0; lo.y = (f16)p1; lo.z = (f16)p2; lo.w = (f16)p3;
            hi.x = (f16)p4; hi.y = (f16)p5; hi.z = (f16)p6; hi.w = (f16)p7;
            *(f16x4*)(sm + LPc + q * 40 + quad * 4)      = lo;  // keys quad*4..+3
            *(f16x4*)(sm + LPc + q * 40 + 16 + quad * 4) = hi;  // keys 16+quad*4..+3
        }

        unsigned long long bm = __ballot(up);
        if (lane == 0) fw[w] = (bm != 0ULL) ? 1 : 0;
        if (quad == 0) aw[w * 16 + l15] = al;

        // ---- single barrier: P/alpha/flags(t) visible; K(t+1)/V(t) landed ----
        asm volatile("s_waitcnt vmcnt(0) lgkmcnt(0)" ::: "memory");
        __builtin_amdgcn_s_barrier();
        __builtin_amdgcn_sched_barrier(0);
    }

    // ---- final PV(63) (buffers at parity of t=63 -> cur=1) ----
    do_pv(LPA + 5120, LVA + 16384,
          (const float*)(sm + LAA + 256), (const int*)(sm + LFA + 16));

    // ---- epilogue: O /= l, store ----
    float* lptr = (float*)(sm + LLL);
    if (quad == 0) lptr[w * 16 + l15] = l_r;
    __syncthreads();
    float linv[16];
#pragma unroll
    for (int r = 0; r < 16; ++r) {
        int row = (r & 3) + ((r >> 2) << 3) + (lhi << 2);
        linv[r] = 1.0f / lptr[qquad * 32 + row];
    }
#pragma unroll
    for (int n = 0; n < 8; ++n) {
#pragma unroll
        for (int r = 0; r < 16; ++r) {
            int row = (r & 3) + ((r >> 2) << 3) + (lhi << 2);
            Y[((size_t)(b * SS + q0 + qquad * 32 + row)) * 512 + dvhalf * 256 + n * 32 + l31] =
                O[n][r] * linv[r];
        }
    }
}

// ---------------------------------------------------------------------------
// Host launcher
// ---------------------------------------------------------------------------
extern "C" void kernel_launch(void* const* d_in, const int* in_sizes, int n_in,
                              void* d_out, int out_size, void* d_ws, size_t ws_size,
                              hipStream_t stream)
{
    const float* x  = (const float*)d_in[0];
    const float* We = (const float*)d_in[1];
    const float* Wk = (const float*)d_in[2];
    const float* Wq = (const float*)d_in[3];
    const float* Wv = (const float*)d_in[4];
    float* out = (float*)d_out;

    const size_t WSZ = 3 * 256 * 512;          // 393216
    const size_t XSZ = (size_t)BB * SS * DIN;  // 8388608
    const size_t MSZ = (size_t)BB * SS * 512;  // 16777216

    f16* Wth = (f16*)d_ws;
    f16* Wtl = Wth + WSZ;
    f16* Xh  = Wtl + WSZ;
    f16* Xl  = Xh + XSZ;
    f16* Qh  = Xl + XSZ;
    f16* Kh  = Qh + MSZ;
    f16* Vt2 = Kh + MSZ;

    prep_x<<<dim3(XSZ / 4 / 256), dim3(256), 0, stream>>>(x, Xh, Xl);

    fuse_weights<<<dim3(1536), dim3(256), 0, stream>>>(We, Wk, Wq, Wv, Wth, Wtl);

    qkv_gemm<<<dim3(4, 256, 3), dim3(256), 0, stream>>>(
        Xh, Xl, Wth, Wtl, Kh, Qh, Vt2);

    attn2<<<dim3(256), dim3(512), 0, stream>>>(Qh, Kh, Vt2, out);
}

// Round 4
// 442.256 us; speedup vs baseline: 1.5501x; 1.0587x over previous
//
#include <hip/hip_runtime.h>
#include <math.h>

// Problem dims (fixed)
#define BB   16
#define SS   2048
#define DIN  256
#define DEMB 512
#define DKQ  512
#define DVV  512

typedef _Float16 f16;
typedef _Float16 half8  __attribute__((ext_vector_type(8)));
typedef _Float16 f16x4  __attribute__((ext_vector_type(4)));
typedef float    f32x4  __attribute__((ext_vector_type(4)));
typedef float    f32x16 __attribute__((ext_vector_type(16)));

#define GLOAD_LDS16(gp, lp)                                                        \
  __builtin_amdgcn_global_load_lds(                                                \
      (const __attribute__((address_space(1))) unsigned int*)(gp),                 \
      (__attribute__((address_space(3))) unsigned int*)(lp), 16, 0, 0)

// V slot permute: decorrelates LDS bank-start across dv rows (2-way max)
__device__ __forceinline__ int vperm(int dv) { return (dv ^ (dv >> 2)) & 3; }

// ---------------------------------------------------------------------------
// Kernel 0: split x (fp32) -> Xh, Xl (fp16 pair, exact to ~2^-22)
// ---------------------------------------------------------------------------
__global__ __launch_bounds__(256) void prep_x(
    const float* __restrict__ x, f16* __restrict__ Xh, f16* __restrict__ Xl)
{
    int idx = blockIdx.x * 256 + threadIdx.x;
    float4 v = ((const float4*)x)[idx];
    f16x4 h, l;
    h.x = (f16)v.x; l.x = (f16)(v.x - (float)h.x);
    h.y = (f16)v.y; l.y = (f16)(v.y - (float)h.y);
    h.z = (f16)v.z; l.z = (f16)(v.z - (float)h.z);
    h.w = (f16)v.w; l.w = (f16)(v.w - (float)h.w);
    ((f16x4*)Xh)[idx] = h;
    ((f16x4*)Xl)[idx] = l;
}

// ---------------------------------------------------------------------------
// Kernel 1: fuse weights W' = W_embed @ W (fp32 math), output TRANSPOSED
// Wth [z][n=512][k=256], f16 (high part only — low part is below the f16
// storage rounding of K/Q/V and is never consumed downstream).
// Tiled: block = 256 n-cols x 8 m-rows; Wsrc panel read once per block
// (L2 traffic 786MB -> 96MB); We rows via uniform scalar loads.
// ---------------------------------------------------------------------------
__global__ __launch_bounds__(256) void fuse_weights(
    const float* __restrict__ We, const float* __restrict__ Wk,
    const float* __restrict__ Wq, const float* __restrict__ Wv,
    f16* __restrict__ Wth)
{
    const int n  = blockIdx.x * 256 + threadIdx.x;   // 0..511
    const int m0 = blockIdx.y * 8;                   // 8 m-rows per block
    const int z  = blockIdx.z;
    const float* Wsrc = (z == 0) ? Wk : (z == 1) ? Wq : Wv;

    float acc[8];
#pragma unroll
    for (int j = 0; j < 8; ++j) acc[j] = 0.f;

#pragma unroll 8
    for (int kk = 0; kk < DEMB; ++kk) {
        float wv = Wsrc[kk * 512 + n];
#pragma unroll
        for (int j = 0; j < 8; ++j)
            acc[j] += We[(m0 + j) * DEMB + kk] * wv;
    }
#pragma unroll
    for (int j = 0; j < 8; ++j)
        Wth[(size_t)z * 131072 + n * 256 + m0 + j] = (f16)acc[j];
}

// ---------------------------------------------------------------------------
// Kernel 2: MFMA projections, 2-term fp16 split (Ah*Bh + Al*Bh = X * W'h,
// exact in X). Tile 128x128, K-chunk 64, 4 waves, 48KB LDS -> 3 blocks/CU.
//   z=0 -> Kh [row][512]; z=1 -> Qh [row][512] PRE-SCALED by log2(e);
//   z=2 -> Vt2 [b][tile(64)][dv(512)][32 keys], 16B slots permuted by vperm(dv)
// ---------------------------------------------------------------------------
#define QAH 0
#define QAL 8192
#define QBH 16384

__global__ __launch_bounds__(256) void qkv_gemm(
    const f16* __restrict__ Xh, const f16* __restrict__ Xl,
    const f16* __restrict__ Wth,
    f16* __restrict__ Kh, f16* __restrict__ Qh, f16* __restrict__ Vt2)
{
    __shared__ __align__(16) short smq[24576];   // 48 KB

    const int tid  = threadIdx.x;
    const int lane = tid & 63;
    const int w    = tid >> 6;
    const int z    = blockIdx.z;
    const int m0   = blockIdx.y * 128;
    const int n0   = blockIdx.x * 128;
    const int l15  = lane & 15;
    const int quad = lane >> 4;
    const int wm   = (w >> 1) * 64, wn = (w & 1) * 64;

    const f16* Bh = Wth + (size_t)z * 131072;

    f32x4 acc[4][4];
#pragma unroll
    for (int i = 0; i < 4; ++i)
#pragma unroll
        for (int j = 0; j < 4; ++j) acc[i][j] = (f32x4){0.f, 0.f, 0.f, 0.f};

    const int lrow = lane >> 3;
    const int lswz = ((lane & 7) ^ (lrow & 7)) << 3;

    for (int c = 0; c < 4; ++c) {
        const int k0 = c * 64;
#pragma unroll
        for (int i = 0; i < 4; ++i) {
            int r0 = w * 32 + i * 8;
            int row = r0 + lrow;
            GLOAD_LDS16(Xh + (size_t)(m0 + row) * 256 + k0 + lswz, smq + QAH + r0 * 64);
            GLOAD_LDS16(Xl + (size_t)(m0 + row) * 256 + k0 + lswz, smq + QAL + r0 * 64);
            GLOAD_LDS16(Bh + (size_t)(n0 + row) * 256 + k0 + lswz, smq + QBH + r0 * 64);
        }
        __syncthreads();
#pragma unroll
        for (int ks = 0; ks < 2; ++ks) {
            const int kg = ks * 4 + quad;
            const int rsw = (kg ^ (l15 & 7)) << 3;
            half8 ah[4], al[4], bh[4];
#pragma unroll
            for (int i = 0; i < 4; ++i) {
                int m = wm + i * 16 + l15;
                int n = wn + i * 16 + l15;
                ah[i] = *(const half8*)(smq + QAH + m * 64 + rsw);
                al[i] = *(const half8*)(smq + QAL + m * 64 + rsw);
                bh[i] = *(const half8*)(smq + QBH + n * 64 + rsw);
            }
#pragma unroll
            for (int mi = 0; mi < 4; ++mi)
#pragma unroll
                for (int ni = 0; ni < 4; ++ni) {
                    acc[mi][ni] = __builtin_amdgcn_mfma_f32_16x16x32_f16(ah[mi], bh[ni], acc[mi][ni], 0, 0, 0);
                    acc[mi][ni] = __builtin_amdgcn_mfma_f32_16x16x32_f16(al[mi], bh[ni], acc[mi][ni], 0, 0, 0);
                }
        }
        __syncthreads();
    }

    // ---- epilogue via LDS (stride 136 shorts; 128*136=17408 <= 24576) ----
    if (z < 2) {
        // Q (z==1) is pre-scaled by log2(e) so attention can use raw exp2.
        const float qsc = (z == 1) ? 1.44269504f : 1.0f;
#pragma unroll
        for (int mi = 0; mi < 4; ++mi)
#pragma unroll
            for (int ni = 0; ni < 4; ++ni)
#pragma unroll
                for (int r = 0; r < 4; ++r)
                    *(f16*)(smq + (wm + mi * 16 + quad * 4 + r) * 136 + wn + ni * 16 + l15) =
                        (f16)(acc[mi][ni][r] * qsc);
        __syncthreads();
        f16* Out = (z == 0) ? Kh : Qh;
        int cg = tid & 15;
#pragma unroll
        for (int j = 0; j < 8; ++j) {
            int row = j * 16 + (tid >> 4);
            half8 v = *(const half8*)(smq + row * 136 + cg * 8);
            *(half8*)&Out[(size_t)(m0 + row) * 512 + n0 + cg * 8] = v;
        }
    } else {
        // transpose in LDS: [dv_local][key_local]
#pragma unroll
        for (int mi = 0; mi < 4; ++mi)
#pragma unroll
            for (int ni = 0; ni < 4; ++ni)
#pragma unroll
                for (int r = 0; r < 4; ++r)
                    *(f16*)(smq + (wn + ni * 16 + l15) * 136 + wm + mi * 16 + quad * 4 + r) =
                        (f16)acc[mi][ni][r];
        __syncthreads();
        int bb = m0 >> 11, kb0 = m0 & 2047;
        int cg = tid & 15;
#pragma unroll
        for (int j = 0; j < 8; ++j) {
            int dvr = j * 16 + (tid >> 4);
            int dv  = n0 + dvr;
            half8 v = *(const half8*)(smq + dvr * 136 + cg * 8);
            int t  = (kb0 >> 5) + (cg >> 2);     // key tile
            int s  = (cg & 3) ^ vperm(dv);       // permuted 16B slot
            *(half8*)&Vt2[(((size_t)bb * 64 + t) * 512 + dv) * 32 + s * 8] = v;
        }
    }
}

// ---------------------------------------------------------------------------
// Kernel 3: MFMA flash attention — ONE barrier per tile (R3, verified 222us),
// SWAPPED-OPERAND scores + lane-local softmax. UNCHANGED from R3.
// ---------------------------------------------------------------------------
#define LKA 0        // K buf0: 32 keys x 512 d   = 16384 shorts
#define LKB 16384    // K buf1
#define LVA 32768    // V buf0: 512 dv x 32 keys  = 16384 shorts
#define LVB 49152    // V buf1
#define LPA 65536    // P buf0: 128 q x stride 40 =  5120 shorts
#define LPB 70656    // P buf1
#define LAA 75776    // alpha buf0/buf1: 2 x 128 floats = 512 shorts
#define LLL 76288    // l[128] floats             =   256 shorts
#define LFA 76544    // flags buf0/buf1: 2 x 8 ints = 32 shorts
#define LTOT 76576   // 153152 bytes (< 160 KiB)

#define THR_L2 11.5416f   // defer-max threshold: 8 nats in log2 units

__global__ __launch_bounds__(512, 2) void attn2(
    const f16* __restrict__ Qh, const f16* __restrict__ Kh,
    const f16* __restrict__ Vt2, float* __restrict__ Y)
{
    __shared__ __align__(16) short sm[LTOT];

    const int tid  = threadIdx.x;
    const int lane = tid & 63;
    const int w    = tid >> 6;                    // 0..7
    // XCD-aware decode: xcd = gid&7; b = (gid&7) + 8*(gid>>7); q0 = ((gid>>3)&15)*128
    const int gid  = blockIdx.x;
    const int b    = (gid & 7) + ((gid >> 7) << 3);
    const int q0   = ((gid >> 3) & 15) << 7;
    const int l15  = lane & 15;
    const int quad = lane >> 4;
    const int l31  = lane & 31;
    const int lhi  = lane >> 5;
    const int qquad = w >> 1, dvhalf = w & 1;     // PV mapping: 4 q-quads x 2 dv-halves

    const f16* Khb  = Kh  + (size_t)b * SS * 512;
    const f16* Vt2b = Vt2 + (size_t)b * 64 * 512 * 32;

    // ---- Q fragments (resident): wave w, q rows q0+16w .. +15 ----
    half8 qh[16];
    {
        const half8* qhp = (const half8*)(Qh + ((size_t)(b * SS + q0 + w * 16 + l15)) * 512);
#pragma unroll
        for (int ks = 0; ks < 16; ++ks) qh[ks] = qhp[ks * 4 + quad];
    }

    f32x16 O[8];
#pragma unroll
    for (int n = 0; n < 8; ++n)
#pragma unroll
        for (int r = 0; r < 16; ++r) O[n][r] = 0.f;

    float m_pr = -1e30f;   // running max, log2 domain (per lane's q row)
    float l_r  = 0.f;      // running denom (per lane's q row)

    // 8 waves x 4 instrs = 32 KB per tile for each of K and V
    auto stage_K = [&](int t, int lk) {
        const int kb = t * 32;
#pragma unroll
        for (int i = 0; i < 4; ++i) {
            int key = w * 4 + i;
            const f16* g = Khb + ((size_t)(kb + key)) * 512 + ((lane ^ (key & 15)) << 3);
            GLOAD_LDS16(g, sm + lk + key * 512);
        }
    };
    auto stage_V = [&](int t, int lv) {
        const f16* gbase = Vt2b + (size_t)t * 16384 + lane * 8;
#pragma unroll
        for (int i = 0; i < 4; ++i) {
            int off = (w * 4 + i) * 512;
            GLOAD_LDS16(gbase + off, sm + lv + off);
        }
    };

    // ---- PV(tp): rescale O by alpha(tp) then O += P(tp) * V(tp) ----
    auto do_pv = [&](int LPp, int LVp, const float* ap, const int* fp) {
        if (fp[2 * qquad] | fp[2 * qquad + 1]) {
            float av[16];
#pragma unroll
            for (int r = 0; r < 16; ++r) {
                int row = (r & 3) + ((r >> 2) << 3) + (lhi << 2);
                av[r] = ap[qquad * 32 + row];
            }
#pragma unroll
            for (int n = 0; n < 8; ++n)
#pragma unroll
                for (int r = 0; r < 16; ++r) O[n][r] *= av[r];
        }
        half8 pA[2];
#pragma unroll
        for (int ks = 0; ks < 2; ++ks) {
            int q  = qquad * 32 + l31;
            int uk = ks * 2 + lhi;
            pA[ks] = *(const half8*)(sm + LPp + q * 40 + uk * 8);
        }
#pragma unroll
        for (int ks = 0; ks < 2; ++ks) {
#pragma unroll
            for (int n = 0; n < 8; ++n) {
                int dv = dvhalf * 256 + n * 32 + l31;
                int uk = ks * 2 + lhi;
                half8 bf = *(const half8*)(sm + LVp + dv * 32 + ((uk ^ vperm(dv)) << 3));
                O[n] = __builtin_amdgcn_mfma_f32_32x32x16_f16(pA[ks], bf, O[n], 0, 0, 0);
            }
        }
    };

    // ---- prologue: stage K(0) into buf0, sync ----
    stage_K(0, LKA);
    asm volatile("s_waitcnt vmcnt(0)" ::: "memory");
    __builtin_amdgcn_s_barrier();
    __builtin_amdgcn_sched_barrier(0);

    for (int t = 0; t < 64; ++t) {
        const int cur = t & 1;
        const int prv = cur ^ 1;
        const int LKc = LKA + cur * 16384;   // K(t)
        const int LKn = LKA + prv * 16384;   // K(t+1) dest
        const int LVc = LVA + cur * 16384;   // V(t) dest
        const int LVp = LVA + prv * 16384;   // V(t-1)
        const int LPc = LPA + cur * 5120;    // P(t) dest
        const int LPp = LPA + prv * 5120;    // P(t-1)
        float* aw = (float*)(sm + LAA + cur * 256);
        const float* ap = (const float*)(sm + LAA + prv * 256);
        int* fw = (int*)(sm + LFA + cur * 16);
        const int* fp = (const int*)(sm + LFA + prv * 16);

        // prefetch: K(t+1) and V(t); both consumed NEXT interval
        if (t + 1 < 64) stage_K(t + 1, LKn);
        stage_V(t, LVc);

        __builtin_amdgcn_s_setprio(1);
        // ---- PV(t-1) ----
        if (t > 0) do_pv(LPp, LVp, ap, fp);

        // ---- scores(t), SWAPPED: S^T = K * Q^T (16x16x32) ----
        // A = K frag (identical LDS addresses as before), B = qh (resident).
        // C: col=l15=q, row=quad*4+r = key (within n*16 block).
        f32x4 S[2];
        S[0] = (f32x4){0.f, 0.f, 0.f, 0.f};
        S[1] = (f32x4){0.f, 0.f, 0.f, 0.f};
#pragma unroll
        for (int ks = 0; ks < 16; ++ks) {
#pragma unroll
            for (int n = 0; n < 2; ++n) {
                int key = n * 16 + l15;
                int ud  = ks * 4 + quad;
                half8 bf = *(const half8*)(sm + LKc + key * 512 + ((ud ^ l15) << 3));
                S[n] = __builtin_amdgcn_mfma_f32_16x16x32_f16(bf, qh[ks], S[n], 0, 0, 0);
            }
        }
        __builtin_amdgcn_s_setprio(0);

        // ---- lane-local online softmax (log2 domain), defer-max ----
        // lane's q row: q = w*16 + l15; lane's 8 keys: n*16 + quad*4 + r
        float mx = fmaxf(fmaxf(fmaxf(S[0][0], S[0][1]), fmaxf(S[0][2], S[0][3])),
                         fmaxf(fmaxf(S[1][0], S[1][1]), fmaxf(S[1][2], S[1][3])));
        mx = fmaxf(mx, __shfl_xor(mx, 16, 64));
        mx = fmaxf(mx, __shfl_xor(mx, 32, 64));
        bool up  = mx > m_pr + THR_L2;          // defer small max growth
        float mn = up ? mx : m_pr;
        float al = up ? __builtin_amdgcn_exp2f(m_pr - mn) : 1.0f;
        m_pr = mn;

        float p0 = __builtin_amdgcn_exp2f(S[0][0] - mn);
        float p1 = __builtin_amdgcn_exp2f(S[0][1] - mn);
        float p2 = __builtin_amdgcn_exp2f(S[0][2] - mn);
        float p3 = __builtin_amdgcn_exp2f(S[0][3] - mn);
        float p4 = __builtin_amdgcn_exp2f(S[1][0] - mn);
        float p5 = __builtin_amdgcn_exp2f(S[1][1] - mn);
        float p6 = __builtin_amdgcn_exp2f(S[1][2] - mn);
        float p7 = __builtin_amdgcn_exp2f(S[1][3] - mn);
        float sum = ((p0 + p1) + (p2 + p3)) + ((p4 + p5) + (p6 + p7));
        sum += __shfl_xor(sum, 16, 64);
        sum += __shfl_xor(sum, 32, 64);
        l_r = l_r * al + sum;

        {
            int q = w * 16 + l15;
            f16x4 lo, hi;
            lo.x = (f16)p0; lo.y = (f16)p1; lo.z = (f16)p2; lo.w = (f16)p3;
            hi.x = (f16)p4; hi.y = (f16)p5; hi.z = (f16)p6; hi.w = (f16)p7;
            *(f16x4*)(sm + LPc + q * 40 + quad * 4)      = lo;  // keys quad*4..+3
            *(f16x4*)(sm + LPc + q * 40 + 16 + quad * 4) = hi;  // keys 16+quad*4..+3
        }

        unsigned long long bm = __ballot(up);
        if (lane == 0) fw[w] = (bm != 0ULL) ? 1 : 0;
        if (quad == 0) aw[w * 16 + l15] = al;

        // ---- single barrier: P/alpha/flags(t) visible; K(t+1)/V(t) landed ----
        asm volatile("s_waitcnt vmcnt(0) lgkmcnt(0)" ::: "memory");
        __builtin_amdgcn_s_barrier();
        __builtin_amdgcn_sched_barrier(0);
    }

    // ---- final PV(63) (buffers at parity of t=63 -> cur=1) ----
    do_pv(LPA + 5120, LVA + 16384,
          (const float*)(sm + LAA + 256), (const int*)(sm + LFA + 16));

    // ---- epilogue: O /= l, store ----
    float* lptr = (float*)(sm + LLL);
    if (quad == 0) lptr[w * 16 + l15] = l_r;
    __syncthreads();
    float linv[16];
#pragma unroll
    for (int r = 0; r < 16; ++r) {
        int row = (r & 3) + ((r >> 2) << 3) + (lhi << 2);
        linv[r] = 1.0f / lptr[qquad * 32 + row];
    }
#pragma unroll
    for (int n = 0; n < 8; ++n) {
#pragma unroll
        for (int r = 0; r < 16; ++r) {
            int row = (r & 3) + ((r >> 2) << 3) + (lhi << 2);
            Y[((size_t)(b * SS + q0 + qquad * 32 + row)) * 512 + dvhalf * 256 + n * 32 + l31] =
                O[n][r] * linv[r];
        }
    }
}

// ---------------------------------------------------------------------------
// Host launcher
// ---------------------------------------------------------------------------
extern "C" void kernel_launch(void* const* d_in, const int* in_sizes, int n_in,
                              void* d_out, int out_size, void* d_ws, size_t ws_size,
                              hipStream_t stream)
{
    const float* x  = (const float*)d_in[0];
    const float* We = (const float*)d_in[1];
    const float* Wk = (const float*)d_in[2];
    const float* Wq = (const float*)d_in[3];
    const float* Wv = (const float*)d_in[4];
    float* out = (float*)d_out;

    const size_t WSZ = 3 * 256 * 512;          // 393216
    const size_t XSZ = (size_t)BB * SS * DIN;  // 8388608
    const size_t MSZ = (size_t)BB * SS * 512;  // 16777216

    f16* Wth = (f16*)d_ws;
    f16* Wtl = Wth + WSZ;                      // (unused slot kept for layout)
    f16* Xh  = Wtl + WSZ;
    f16* Xl  = Xh + XSZ;
    f16* Qh  = Xl + XSZ;
    f16* Kh  = Qh + MSZ;
    f16* Vt2 = Kh + MSZ;

    prep_x<<<dim3(XSZ / 4 / 256), dim3(256), 0, stream>>>(x, Xh, Xl);

    fuse_weights<<<dim3(2, 32, 3), dim3(256), 0, stream>>>(We, Wk, Wq, Wv, Wth);

    qkv_gemm<<<dim3(4, 256, 3), dim3(256), 0, stream>>>(
        Xh, Xl, Wth, Kh, Qh, Vt2);

    attn2<<<dim3(256), dim3(512), 0, stream>>>(Qh, Kh, Vt2, out);
}

// Round 5
// 402.645 us; speedup vs baseline: 1.7026x; 1.0984x over previous
//
#include <hip/hip_runtime.h>
#include <math.h>

// Problem dims (fixed)
#define BB   16
#define SS   2048
#define DIN  256
#define DEMB 512
#define DKQ  512
#define DVV  512

typedef _Float16 f16;
typedef _Float16 half8  __attribute__((ext_vector_type(8)));
typedef _Float16 f16x4  __attribute__((ext_vector_type(4)));
typedef float    f32x4  __attribute__((ext_vector_type(4)));
typedef float    f32x16 __attribute__((ext_vector_type(16)));

#define GLOAD_LDS16(gp, lp)                                                        \
  __builtin_amdgcn_global_load_lds(                                                \
      (const __attribute__((address_space(1))) unsigned int*)(gp),                 \
      (__attribute__((address_space(3))) unsigned int*)(lp), 16, 0, 0)

// V slot permute: decorrelates LDS bank-start across dv rows (2-way max)
__device__ __forceinline__ int vperm(int dv) { return (dv ^ (dv >> 2)) & 3; }

// ---------------------------------------------------------------------------
// Kernel 0: split x (fp32) -> Xh, Xl (fp16 pair, exact to ~2^-22)
// ---------------------------------------------------------------------------
__global__ __launch_bounds__(256) void prep_x(
    const float* __restrict__ x, f16* __restrict__ Xh, f16* __restrict__ Xl)
{
    int idx = blockIdx.x * 256 + threadIdx.x;
    float4 v = ((const float4*)x)[idx];
    f16x4 h, l;
    h.x = (f16)v.x; l.x = (f16)(v.x - (float)h.x);
    h.y = (f16)v.y; l.y = (f16)(v.y - (float)h.y);
    h.z = (f16)v.z; l.z = (f16)(v.z - (float)h.z);
    h.w = (f16)v.w; l.w = (f16)(v.w - (float)h.w);
    ((f16x4*)Xh)[idx] = h;
    ((f16x4*)Xl)[idx] = l;
}

// ---------------------------------------------------------------------------
// Kernel 1: fuse weights W' = W_embed @ W (fp32 math), output TRANSPOSED
// Wth [z][n=512][k=256], f16 high part. Tiled: block = 256 n-cols x 8 m-rows.
// ---------------------------------------------------------------------------
__global__ __launch_bounds__(256) void fuse_weights(
    const float* __restrict__ We, const float* __restrict__ Wk,
    const float* __restrict__ Wq, const float* __restrict__ Wv,
    f16* __restrict__ Wth)
{
    const int n  = blockIdx.x * 256 + threadIdx.x;   // 0..511
    const int m0 = blockIdx.y * 8;                   // 8 m-rows per block
    const int z  = blockIdx.z;
    const float* Wsrc = (z == 0) ? Wk : (z == 1) ? Wq : Wv;

    float acc[8];
#pragma unroll
    for (int j = 0; j < 8; ++j) acc[j] = 0.f;

#pragma unroll 8
    for (int kk = 0; kk < DEMB; ++kk) {
        float wv = Wsrc[kk * 512 + n];
#pragma unroll
        for (int j = 0; j < 8; ++j)
            acc[j] += We[(m0 + j) * DEMB + kk] * wv;
    }
#pragma unroll
    for (int j = 0; j < 8; ++j)
        Wth[(size_t)z * 131072 + n * 256 + m0 + j] = (f16)acc[j];
}

// ---------------------------------------------------------------------------
// Kernel 2: MFMA projections, 2-term fp16 split (Ah*Bh + Al*Bh = X*W'h).
// REBUILT on the attn2-proven schedule: tile 256m x 128n, 8 waves, K-chunks
// of 64 (4 chunks), double-buffered staging (80 KB/buf, 160 KiB LDS total),
// ONE barrier per chunk: stage(c+1) issued at interval top, vmcnt(0) only at
// the barrier -> full-interval prefetch window. setprio(1) around MFMAs.
// XCD-ownership remap: xcd = gid&7 owns m-panels [xcd*16, +16) for ALL
// (n,z) -> per-XCD working set = 4 MB A + 0.77 MB B = L2-resident; global
// re-reads become L2 hits (was 576 MB of L3/HBM traffic).
//   z=0 -> Kh [row][512]; z=1 -> Qh [row][512] PRE-SCALED by log2(e);
//   z=2 -> Vt2 [b][tile(64)][dv(512)][32 keys], 16B slots permuted by vperm(dv)
// ---------------------------------------------------------------------------
#define GAH 0        // A-high: 256 rows x 64 k = 16384 shorts
#define GAL 16384    // A-low
#define GBH 32768    // B-high: 128 rows x 64 k = 8192 shorts
#define GBUF 40960   // one buffer = 40960 shorts (80 KB); x2 = 160 KiB

__global__ __launch_bounds__(512) void qkv_gemm(
    const f16* __restrict__ Xh, const f16* __restrict__ Xl,
    const f16* __restrict__ Wth,
    f16* __restrict__ Kh, f16* __restrict__ Qh, f16* __restrict__ Vt2)
{
    __shared__ __align__(16) short smq[81920];   // 160 KiB

    const int tid  = threadIdx.x;
    const int lane = tid & 63;
    const int w    = tid >> 6;                   // 0..7
    const int l15  = lane & 15;
    const int quad = lane >> 4;

    // XCD-ownership decode: xcd owns 16 contiguous m-panels for all (n,z).
    const int gid = blockIdx.x;                  // 0..1535
    const int xcd = gid & 7;
    const int j   = gid >> 3;                    // 0..191
    const int ml  = j / 12;                      // 0..15
    const int rem = j - ml * 12;
    const int nb  = rem & 3;
    const int z   = rem >> 2;
    const int m0  = (xcd * 16 + ml) * 256;
    const int n0  = nb * 128;

    const int wmB = (w >> 1) * 64;               // wave m-base (0..192)
    const int wnB = (w & 1) * 64;                // wave n-base (0 or 64)

    const f16* Bh = Wth + (size_t)z * 131072;

    f32x4 acc[4][4];
#pragma unroll
    for (int i = 0; i < 4; ++i)
#pragma unroll
        for (int jj = 0; jj < 4; ++jj) acc[i][jj] = (f32x4){0.f, 0.f, 0.f, 0.f};

    const int lrow = lane >> 3;
    const int lswz = ((lane & 7) ^ (lrow & 7)) << 3;

    // Stage chunk c (K = c*64 .. +64) into buffer `buf`.
    // A rows: wave w stages [w*32, +32); B rows: [w*16, +16).
    auto stage = [&](int c, int buf) {
        const int k0 = c * 64;
#pragma unroll
        for (int i = 0; i < 4; ++i) {
            int r0  = w * 32 + i * 8;
            int row = r0 + lrow;
            GLOAD_LDS16(Xh + (size_t)(m0 + row) * 256 + k0 + lswz, smq + buf + GAH + r0 * 64);
            GLOAD_LDS16(Xl + (size_t)(m0 + row) * 256 + k0 + lswz, smq + buf + GAL + r0 * 64);
        }
#pragma unroll
        for (int i = 0; i < 2; ++i) {
            int r0  = w * 16 + i * 8;
            int row = r0 + lrow;
            GLOAD_LDS16(Bh + (size_t)(n0 + row) * 256 + k0 + lswz, smq + buf + GBH + r0 * 64);
        }
    };

    // ---- prologue: stage chunk 0 into buf0 ----
    stage(0, 0);
    asm volatile("s_waitcnt vmcnt(0)" ::: "memory");
    __builtin_amdgcn_s_barrier();
    __builtin_amdgcn_sched_barrier(0);

    for (int c = 0; c < 4; ++c) {
        const int bufc = (c & 1) * GBUF;
        const int bufn = ((c + 1) & 1) * GBUF;

        // prefetch next chunk; consumed NEXT interval
        if (c < 3) stage(c + 1, bufn);

        __builtin_amdgcn_s_setprio(1);
#pragma unroll
        for (int ks = 0; ks < 2; ++ks) {
            const int kg  = ks * 4 + quad;
            const int rsw = (kg ^ (l15 & 7)) << 3;
            half8 ah[4], al[4], bh[4];
#pragma unroll
            for (int i = 0; i < 4; ++i) {
                ah[i] = *(const half8*)(smq + bufc + GAH + (wmB + i * 16 + l15) * 64 + rsw);
                al[i] = *(const half8*)(smq + bufc + GAL + (wmB + i * 16 + l15) * 64 + rsw);
                bh[i] = *(const half8*)(smq + bufc + GBH + (wnB + i * 16 + l15) * 64 + rsw);
            }
#pragma unroll
            for (int mi = 0; mi < 4; ++mi)
#pragma unroll
                for (int ni = 0; ni < 4; ++ni) {
                    acc[mi][ni] = __builtin_amdgcn_mfma_f32_16x16x32_f16(ah[mi], bh[ni], acc[mi][ni], 0, 0, 0);
                    acc[mi][ni] = __builtin_amdgcn_mfma_f32_16x16x32_f16(al[mi], bh[ni], acc[mi][ni], 0, 0, 0);
                }
        }
        __builtin_amdgcn_s_setprio(0);

        asm volatile("s_waitcnt vmcnt(0) lgkmcnt(0)" ::: "memory");
        __builtin_amdgcn_s_barrier();
        __builtin_amdgcn_sched_barrier(0);
    }

    // ---- epilogue via LDS (reuses buf0 region; all compute done) ----
    if (z < 2) {
        // stride 136 shorts; 256 x 136 = 34816 shorts <= 40960 (buf0)
        const float qsc = (z == 1) ? 1.44269504f : 1.0f;
#pragma unroll
        for (int mi = 0; mi < 4; ++mi)
#pragma unroll
            for (int ni = 0; ni < 4; ++ni)
#pragma unroll
                for (int r = 0; r < 4; ++r)
                    *(f16*)(smq + (wmB + mi * 16 + quad * 4 + r) * 136 + wnB + ni * 16 + l15) =
                        (f16)(acc[mi][ni][r] * qsc);
        __syncthreads();
        f16* Out = (z == 0) ? Kh : Qh;
        int cg = tid & 15;
        int rt = tid >> 4;                       // 0..31
#pragma unroll
        for (int jj = 0; jj < 8; ++jj) {
            int row = jj * 32 + rt;
            half8 v = *(const half8*)(smq + row * 136 + cg * 8);
            *(half8*)&Out[(size_t)(m0 + row) * 512 + n0 + cg * 8] = v;
        }
    } else {
        // transpose in LDS: [dv_local 128][key_local 256], stride 264
        // 128 x 264 = 33792 shorts <= 40960 (buf0)
#pragma unroll
        for (int mi = 0; mi < 4; ++mi)
#pragma unroll
            for (int ni = 0; ni < 4; ++ni)
#pragma unroll
                for (int r = 0; r < 4; ++r)
                    *(f16*)(smq + (wnB + ni * 16 + l15) * 264 + wmB + mi * 16 + quad * 4 + r) =
                        (f16)acc[mi][ni][r];
        __syncthreads();
        int bb = m0 >> 11, kb0 = m0 & 2047;
        int cg = tid & 31;                       // key 16B-group 0..31 (256 keys)
        int rt = tid >> 5;                       // 0..15
#pragma unroll
        for (int jj = 0; jj < 8; ++jj) {
            int dvr = jj * 16 + rt;              // 0..127
            int dv  = n0 + dvr;
            half8 v = *(const half8*)(smq + dvr * 264 + cg * 8);
            int t  = (kb0 >> 5) + (cg >> 2);     // key tile
            int s  = (cg & 3) ^ vperm(dv);       // permuted 16B slot
            *(half8*)&Vt2[(((size_t)bb * 64 + t) * 512 + dv) * 32 + s * 8] = v;
        }
    }
}

// ---------------------------------------------------------------------------
// Kernel 3: MFMA flash attention — ONE barrier per tile (R3, verified 222us),
// SWAPPED-OPERAND scores + lane-local softmax. UNCHANGED.
// ---------------------------------------------------------------------------
#define LKA 0        // K buf0: 32 keys x 512 d   = 16384 shorts
#define LKB 16384    // K buf1
#define LVA 32768    // V buf0: 512 dv x 32 keys  = 16384 shorts
#define LVB 49152    // V buf1
#define LPA 65536    // P buf0: 128 q x stride 40 =  5120 shorts
#define LPB 70656    // P buf1
#define LAA 75776    // alpha buf0/buf1: 2 x 128 floats = 512 shorts
#define LLL 76288    // l[128] floats             =   256 shorts
#define LFA 76544    // flags buf0/buf1: 2 x 8 ints = 32 shorts
#define LTOT 76576   // 153152 bytes (< 160 KiB)

#define THR_L2 11.5416f   // defer-max threshold: 8 nats in log2 units

__global__ __launch_bounds__(512, 2) void attn2(
    const f16* __restrict__ Qh, const f16* __restrict__ Kh,
    const f16* __restrict__ Vt2, float* __restrict__ Y)
{
    __shared__ __align__(16) short sm[LTOT];

    const int tid  = threadIdx.x;
    const int lane = tid & 63;
    const int w    = tid >> 6;                    // 0..7
    // XCD-aware decode: xcd = gid&7; b = (gid&7) + 8*(gid>>7); q0 = ((gid>>3)&15)*128
    const int gid  = blockIdx.x;
    const int b    = (gid & 7) + ((gid >> 7) << 3);
    const int q0   = ((gid >> 3) & 15) << 7;
    const int l15  = lane & 15;
    const int quad = lane >> 4;
    const int l31  = lane & 31;
    const int lhi  = lane >> 5;
    const int qquad = w >> 1, dvhalf = w & 1;     // PV mapping: 4 q-quads x 2 dv-halves

    const f16* Khb  = Kh  + (size_t)b * SS * 512;
    const f16* Vt2b = Vt2 + (size_t)b * 64 * 512 * 32;

    // ---- Q fragments (resident): wave w, q rows q0+16w .. +15 ----
    half8 qh[16];
    {
        const half8* qhp = (const half8*)(Qh + ((size_t)(b * SS + q0 + w * 16 + l15)) * 512);
#pragma unroll
        for (int ks = 0; ks < 16; ++ks) qh[ks] = qhp[ks * 4 + quad];
    }

    f32x16 O[8];
#pragma unroll
    for (int n = 0; n < 8; ++n)
#pragma unroll
        for (int r = 0; r < 16; ++r) O[n][r] = 0.f;

    float m_pr = -1e30f;   // running max, log2 domain (per lane's q row)
    float l_r  = 0.f;      // running denom (per lane's q row)

    // 8 waves x 4 instrs = 32 KB per tile for each of K and V
    auto stage_K = [&](int t, int lk) {
        const int kb = t * 32;
#pragma unroll
        for (int i = 0; i < 4; ++i) {
            int key = w * 4 + i;
            const f16* g = Khb + ((size_t)(kb + key)) * 512 + ((lane ^ (key & 15)) << 3);
            GLOAD_LDS16(g, sm + lk + key * 512);
        }
    };
    auto stage_V = [&](int t, int lv) {
        const f16* gbase = Vt2b + (size_t)t * 16384 + lane * 8;
#pragma unroll
        for (int i = 0; i < 4; ++i) {
            int off = (w * 4 + i) * 512;
            GLOAD_LDS16(gbase + off, sm + lv + off);
        }
    };

    // ---- PV(tp): rescale O by alpha(tp) then O += P(tp) * V(tp) ----
    auto do_pv = [&](int LPp, int LVp, const float* ap, const int* fp) {
        if (fp[2 * qquad] | fp[2 * qquad + 1]) {
            float av[16];
#pragma unroll
            for (int r = 0; r < 16; ++r) {
                int row = (r & 3) + ((r >> 2) << 3) + (lhi << 2);
                av[r] = ap[qquad * 32 + row];
            }
#pragma unroll
            for (int n = 0; n < 8; ++n)
#pragma unroll
                for (int r = 0; r < 16; ++r) O[n][r] *= av[r];
        }
        half8 pA[2];
#pragma unroll
        for (int ks = 0; ks < 2; ++ks) {
            int q  = qquad * 32 + l31;
            int uk = ks * 2 + lhi;
            pA[ks] = *(const half8*)(sm + LPp + q * 40 + uk * 8);
        }
#pragma unroll
        for (int ks = 0; ks < 2; ++ks) {
#pragma unroll
            for (int n = 0; n < 8; ++n) {
                int dv = dvhalf * 256 + n * 32 + l31;
                int uk = ks * 2 + lhi;
                half8 bf = *(const half8*)(sm + LVp + dv * 32 + ((uk ^ vperm(dv)) << 3));
                O[n] = __builtin_amdgcn_mfma_f32_32x32x16_f16(pA[ks], bf, O[n], 0, 0, 0);
            }
        }
    };

    // ---- prologue: stage K(0) into buf0, sync ----
    stage_K(0, LKA);
    asm volatile("s_waitcnt vmcnt(0)" ::: "memory");
    __builtin_amdgcn_s_barrier();
    __builtin_amdgcn_sched_barrier(0);

    for (int t = 0; t < 64; ++t) {
        const int cur = t & 1;
        const int prv = cur ^ 1;
        const int LKc = LKA + cur * 16384;   // K(t)
        const int LKn = LKA + prv * 16384;   // K(t+1) dest
        const int LVc = LVA + cur * 16384;   // V(t) dest
        const int LVp = LVA + prv * 16384;   // V(t-1)
        const int LPc = LPA + cur * 5120;    // P(t) dest
        const int LPp = LPA + prv * 5120;    // P(t-1)
        float* aw = (float*)(sm + LAA + cur * 256);
        const float* ap = (const float*)(sm + LAA + prv * 256);
        int* fw = (int*)(sm + LFA + cur * 16);
        const int* fp = (const int*)(sm + LFA + prv * 16);

        // prefetch: K(t+1) and V(t); both consumed NEXT interval
        if (t + 1 < 64) stage_K(t + 1, LKn);
        stage_V(t, LVc);

        __builtin_amdgcn_s_setprio(1);
        // ---- PV(t-1) ----
        if (t > 0) do_pv(LPp, LVp, ap, fp);

        // ---- scores(t), SWAPPED: S^T = K * Q^T (16x16x32) ----
        f32x4 S[2];
        S[0] = (f32x4){0.f, 0.f, 0.f, 0.f};
        S[1] = (f32x4){0.f, 0.f, 0.f, 0.f};
#pragma unroll
        for (int ks = 0; ks < 16; ++ks) {
#pragma unroll
            for (int n = 0; n < 2; ++n) {
                int key = n * 16 + l15;
                int ud  = ks * 4 + quad;
                half8 bf = *(const half8*)(sm + LKc + key * 512 + ((ud ^ l15) << 3));
                S[n] = __builtin_amdgcn_mfma_f32_16x16x32_f16(bf, qh[ks], S[n], 0, 0, 0);
            }
        }
        __builtin_amdgcn_s_setprio(0);

        // ---- lane-local online softmax (log2 domain), defer-max ----
        float mx = fmaxf(fmaxf(fmaxf(S[0][0], S[0][1]), fmaxf(S[0][2], S[0][3])),
                         fmaxf(fmaxf(S[1][0], S[1][1]), fmaxf(S[1][2], S[1][3])));
        mx = fmaxf(mx, __shfl_xor(mx, 16, 64));
        mx = fmaxf(mx, __shfl_xor(mx, 32, 64));
        bool up  = mx > m_pr + THR_L2;          // defer small max growth
        float mn = up ? mx : m_pr;
        float al = up ? __builtin_amdgcn_exp2f(m_pr - mn) : 1.0f;
        m_pr = mn;

        float p0 = __builtin_amdgcn_exp2f(S[0][0] - mn);
        float p1 = __builtin_amdgcn_exp2f(S[0][1] - mn);
        float p2 = __builtin_amdgcn_exp2f(S[0][2] - mn);
        float p3 = __builtin_amdgcn_exp2f(S[0][3] - mn);
        float p4 = __builtin_amdgcn_exp2f(S[1][0] - mn);
        float p5 = __builtin_amdgcn_exp2f(S[1][1] - mn);
        float p6 = __builtin_amdgcn_exp2f(S[1][2] - mn);
        float p7 = __builtin_amdgcn_exp2f(S[1][3] - mn);
        float sum = ((p0 + p1) + (p2 + p3)) + ((p4 + p5) + (p6 + p7));
        sum += __shfl_xor(sum, 16, 64);
        sum += __shfl_xor(sum, 32, 64);
        l_r = l_r * al + sum;

        {
            int q = w * 16 + l15;
            f16x4 lo, hi;
            lo.x = (f16)p0; lo.y = (f16)p1; lo.z = (f16)p2; lo.w = (f16)p3;
            hi.x = (f16)p4; hi.y = (f16)p5; hi.z = (f16)p6; hi.w = (f16)p7;
            *(f16x4*)(sm + LPc + q * 40 + quad * 4)      = lo;  // keys quad*4..+3
            *(f16x4*)(sm + LPc + q * 40 + 16 + quad * 4) = hi;  // keys 16+quad*4..+3
        }

        unsigned long long bm = __ballot(up);
        if (lane == 0) fw[w] = (bm != 0ULL) ? 1 : 0;
        if (quad == 0) aw[w * 16 + l15] = al;

        // ---- single barrier: P/alpha/flags(t) visible; K(t+1)/V(t) landed ----
        asm volatile("s_waitcnt vmcnt(0) lgkmcnt(0)" ::: "memory");
        __builtin_amdgcn_s_barrier();
        __builtin_amdgcn_sched_barrier(0);
    }

    // ---- final PV(63) (buffers at parity of t=63 -> cur=1) ----
    do_pv(LPA + 5120, LVA + 16384,
          (const float*)(sm + LAA + 256), (const int*)(sm + LFA + 16));

    // ---- epilogue: O /= l, store ----
    float* lptr = (float*)(sm + LLL);
    if (quad == 0) lptr[w * 16 + l15] = l_r;
    __syncthreads();
    float linv[16];
#pragma unroll
    for (int r = 0; r < 16; ++r) {
        int row = (r & 3) + ((r >> 2) << 3) + (lhi << 2);
        linv[r] = 1.0f / lptr[qquad * 32 + row];
    }
#pragma unroll
    for (int n = 0; n < 8; ++n) {
#pragma unroll
        for (int r = 0; r < 16; ++r) {
            int row = (r & 3) + ((r >> 2) << 3) + (lhi << 2);
            Y[((size_t)(b * SS + q0 + qquad * 32 + row)) * 512 + dvhalf * 256 + n * 32 + l31] =
                O[n][r] * linv[r];
        }
    }
}

// ---------------------------------------------------------------------------
// Host launcher
// ---------------------------------------------------------------------------
extern "C" void kernel_launch(void* const* d_in, const int* in_sizes, int n_in,
                              void* d_out, int out_size, void* d_ws, size_t ws_size,
                              hipStream_t stream)
{
    const float* x  = (const float*)d_in[0];
    const float* We = (const float*)d_in[1];
    const float* Wk = (const float*)d_in[2];
    const float* Wq = (const float*)d_in[3];
    const float* Wv = (const float*)d_in[4];
    float* out = (float*)d_out;

    const size_t WSZ = 3 * 256 * 512;          // 393216
    const size_t XSZ = (size_t)BB * SS * DIN;  // 8388608
    const size_t MSZ = (size_t)BB * SS * 512;  // 16777216

    f16* Wth = (f16*)d_ws;
    f16* Wtl = Wth + WSZ;                      // (unused slot kept for layout)
    f16* Xh  = Wtl + WSZ;
    f16* Xl  = Xh + XSZ;
    f16* Qh  = Xl + XSZ;
    f16* Kh  = Qh + MSZ;
    f16* Vt2 = Kh + MSZ;

    prep_x<<<dim3(XSZ / 4 / 256), dim3(256), 0, stream>>>(x, Xh, Xl);

    fuse_weights<<<dim3(2, 32, 3), dim3(256), 0, stream>>>(We, Wk, Wq, Wv, Wth);

    qkv_gemm<<<dim3(1536), dim3(512), 0, stream>>>(
        Xh, Xl, Wth, Kh, Qh, Vt2);

    attn2<<<dim3(256), dim3(512), 0, stream>>>(Qh, Kh, Vt2, out);
}